// Round 11
// baseline (54.397 us; speedup 1.0000x reference)
//
#include <hip/hip_runtime.h>
#include <math.h>

typedef __attribute__((ext_vector_type(8))) short short8v;   // 8 bf16 (4 VGPRs)
typedef __attribute__((ext_vector_type(4))) float f32x4;

namespace {
constexpr int NSAMP = 32768;
constexpr int NMASK = NSAMP - 1;
constexpr float MIN_F_F = (float)(30.0 / 11025.0);
constexpr float SPAN_F  = (float)(3000.0 / 11025.0 - 30.0 / 11025.0);
constexpr float PI_F    = 3.14159265358979323846f;
constexpr double TWO_PI  = 6.283185307179586476925287;
constexpr double INV_2PI = 0.159154943091895335768884;
constexpr float INV_2PI_F = 0.15915494309189533577f;
constexpr float INV_SQRT_N = 0.00552427172801990295f; // 1/sqrt(32768)

// ws layout (bytes)
constexpr size_t OFF_PM = 0;                          // float PmodR [32][64][128]  1 MB
constexpr size_t OFF_V  = OFF_PM + 32*64*128*4;       // float vfreq [32][64][128]  1 MB
constexpr size_t OFF_TA = OFF_V  + 32*64*128*4;       // u16   tapsA [32][64][128]  512 KB
constexpr size_t OFF_A  = OFF_TA + 32*64*128*2;       // float ampT  [32][128fr][128ch] 2 MB
constexpr size_t OFF_M  = OFF_A  + 32*128*128*4;      // uint  maxb  [2048]
constexpr size_t OFF_SW = OFF_M  + 2048*4;            // float swb   [32]
constexpr size_t OFF_SH = OFF_SW + 32*4;              // int   shiftb[32]
constexpr size_t OFF_NM = OFF_SH + 32*4;              // int   nmtb  [32] (active 16-h blocks)
}

__device__ __forceinline__ float sigmoidf_(float z) { return 1.0f / (1.0f + expf(-z)); }
__device__ __forceinline__ float gumbelf_(float u) { return -logf(-logf(u + 1e-10f) + 1e-10f); }
__device__ __forceinline__ unsigned short f2bf(float f) {
    unsigned u = __float_as_uint(f);
    return (unsigned short)((u + 0x7FFFu + ((u >> 16) & 1u)) >> 16);
}
__device__ __forceinline__ float sinrev(float r) {   // r in [0,1): sin(2*pi*r)
#if __has_builtin(__builtin_amdgcn_sinf)
    return __builtin_amdgcn_sinf(r);
#else
    return __sinf(r * 6.2831853071795864769f);
#endif
}

// ---------------- prep: gates, f0, freq table, phase prefixes, bf16 taps, nmt ----------------
__launch_bounds__(256)
__global__ void prep_kernel(const float* __restrict__ x,
                            const float* __restrict__ Wsw, const float* __restrict__ bsw,
                            const float* __restrict__ Wf0, const float* __restrict__ bf0,
                            const float* __restrict__ Wfv, const float* __restrict__ bfv,
                            const float* __restrict__ Wloc, const float* __restrict__ bloc,
                            const float* __restrict__ usw, const float* __restrict__ uloc,
                            float* __restrict__ PmodR, float* __restrict__ vfreq,
                            unsigned short* __restrict__ tapsA, float* __restrict__ swb,
                            int* __restrict__ shiftb, unsigned int* __restrict__ maxb,
                            int* __restrict__ nmtb) {
    int tid = threadIdx.x;
    __shared__ float xs[128], f0t[128];
    __shared__ float redA[128]; __shared__ int redI[128];
    __shared__ float red0[128], red1[128], red2[128];
    __shared__ int maxHsh;

    int b = blockIdx.x;
    if (tid < 64) maxb[b * 64 + tid] = 0u;
    if (tid == 0) maxHsh = 0;
    if (tid < 128) xs[tid] = x[b * 128 + tid];
    __syncthreads();

    // per-frame dots: threads 0..127 -> f0_var logits; 128..255 -> loc logits
    {
        int half = tid >> 7, fr = tid & 127;
        const float* W = half ? Wloc : Wfv;
        float a = (half ? bloc : bfv)[fr];
        for (int d = 0; d < 128; ++d) a = fmaf(xs[d], W[d * 128 + fr], a);
        if (half) { redA[fr] = sigmoidf_(a) + gumbelf_(uloc[b * 128 + fr]); redI[fr] = fr; }
        else      { f0t[fr] = sigmoidf_(a) * 2.0f - 1.0f; }   // f0var stash
    }
    if (tid < 128) {
        red0[tid] = xs[tid] * Wsw[tid * 2 + 0];
        red1[tid] = xs[tid] * Wsw[tid * 2 + 1];
        red2[tid] = xs[tid] * Wf0[tid];
    }
    __syncthreads();
    for (int off = 64; off > 0; off >>= 1) {
        if (tid < off) {
            red0[tid] += red0[tid + off];
            red1[tid] += red1[tid + off];
            red2[tid] += red2[tid + off];
            if (redA[tid + off] > redA[tid]) { redA[tid] = redA[tid + off]; redI[tid] = redI[tid + off]; }
        }
        __syncthreads();
    }
    float l0 = red0[0] + bsw[0], l1 = red1[0] + bsw[1];
    float g0 = gumbelf_(usw[b * 2 + 0]), g1 = gumbelf_(usw[b * 2 + 1]);
    float swv = (l0 + g0 >= l1 + g1) ? 1.0f : 0.0f;
    float sg = sigmoidf_(red2[0] + bf0[0]);
    float f0v = MIN_F_F + (sg * sg) * SPAN_F;
    if (tid == 0) { swb[b] = swv; shiftb[b] = redI[0] * 256; }
    if (tid < 128) {
        float f0var = f0t[tid];
        f0t[tid] = f0v + f0var * (f0v * 0.01f);
    }
    __syncthreads();

    // phase-prefix scan + taps, 4 waves x 16 h each; lane handles k=2l,2l+1
    int wave = tid >> 6, lane = tid & 63;
    int k0 = lane * 2, k1 = k0 + 1;
    int myMaxH = 0;
    for (int h = wave; h < 64; h += 4) {
        float hf = (float)(h + 1);
        size_t base = ((size_t)b * 64 + h) * 128;
        float vA = f0t[k0] * hf; vA = (vA > 1.0f) ? 0.0f : vA * PI_F;
        float vB = f0t[k1] * hf; vB = (vB > 1.0f) ? 0.0f : vB * PI_F;
        if (__any((vA > 0.0f) || (vB > 0.0f))) myMaxH = h;   // activity monotone in h
        double v0d = (double)vA, v1d = (double)vB;
        double sc = v0d + v1d;
#pragma unroll
        for (int d = 1; d < 64; d <<= 1) {
            double o = __shfl_up(sc, d);
            if (lane >= d) sc += o;
        }
        // P(k) = 128*(2*S(k) - v[k]); S(2l+1)=sc, S(2l)=sc-v1
        double P0 = 128.0 * (2.0 * sc - 2.0 * v1d - v0d);
        double P1 = 128.0 * (2.0 * sc - v1d);
        double r0 = P0 * INV_2PI; r0 -= floor(r0);
        double r1 = P1 * INV_2PI; r1 -= floor(r1);
        PmodR[base + k0] = (float)r0;
        PmodR[base + k1] = (float)r1;
        vfreq[base + k0] = vA * INV_2PI_F;
        vfreq[base + k1] = vB * INV_2PI_F;
        // taps (depend only on v0 of this h)
        float v0_rad = __shfl(vA, 0);
        double v0rev = (double)v0_rad * INV_2PI;
#pragma unroll
        for (int kk = 0; kk < 2; ++kk) {
            int k = k0 + kk;
            float hwk = 0.54f - 0.46f * cosf(6.2831853071795864769f * (float)k / 128.0f);
            double rv = (double)(k + 1) * v0rev; rv -= floor(rv);
            float sv = __sinf((float)(rv * TWO_PI));
            float tv = sv * hwk * INV_SQRT_N;
            int c = k >> 3, e = 7 - (k & 7);
            tapsA[base + 8 * (c ^ (h & 7)) + e] = f2bf(tv);
        }
    }
    if (lane == 0) atomicMax(&maxHsh, myMaxH);
    __syncthreads();
    if (tid == 0) nmtb[b] = (maxHsh >> 4) + 1;
}

// Conv core notes:
//   k-fill convention (same for A and B, so any HW k-permutation cancels):
//     frag[r] corresponds to logical k = 32*ks + 8*(lane>>4) + (7 - r)
//   A (taps) stored pre-reversed -> one aligned b128 per (mt,ks)
//   B: wsh[s][t] = w[t+s], chunk c stored at c^s -> one aligned, conflict-free b128
//   Dead-harmonic skip: COMPILE-TIME via template<NMT> + uniform switch (R8 lesson:
//   runtime per-mt guards around MFMA destroy pipelining; R10 lesson: wave-per-mt
//   remap quadruples fb LDS traffic -- keep thread-owns-samples x all-mt mapping).

// ---------------- convmax core ----------------
template<int NMT>
__device__ __forceinline__ void convmax_core(int tid, const short* tapsL,
                                             const short (*wsh)[640],
                                             unsigned int* maxL) {
    int lane = tid & 63, w = tid >> 6;
    int g = lane >> 4, col = lane & 15, s_l = lane & 7, b3 = (lane >> 3) & 1;
    short8v fa[NMT][4];
#pragma unroll
    for (int mt = 0; mt < NMT; ++mt)
#pragma unroll
        for (int ks = 0; ks < 4; ++ks) {
            int row = 16 * mt + col;
            int ch = (4 * ks + g) ^ (row & 7);
            fa[mt][ks] = *(const short8v*)&tapsL[row * 128 + 8 * ch];
        }
    float rm[NMT * 4];
#pragma unroll
    for (int i = 0; i < NMT * 4; ++i) rm[i] = 0.0f;
    for (int ntl = 0; ntl < 8; ++ntl) {
        int nt = w * 8 + ntl;
        short8v fb[4];
#pragma unroll
        for (int ks = 0; ks < 4; ++ks) {
            int t0 = 120 + 16 * nt - 32 * ks - 8 * g + 8 * b3;
            int ch = (t0 >> 3) ^ s_l;
            fb[ks] = *(const short8v*)&wsh[s_l][8 * ch];
        }
        f32x4 acc[NMT];
#pragma unroll
        for (int mt = 0; mt < NMT; ++mt) acc[mt] = (f32x4){0, 0, 0, 0};
#pragma unroll
        for (int ks = 0; ks < 4; ++ks)
#pragma unroll
            for (int mt = 0; mt < NMT; ++mt)
                acc[mt] = __builtin_amdgcn_mfma_f32_16x16x32_bf16(fa[mt][ks], fb[ks], acc[mt], 0, 0, 0);
#pragma unroll
        for (int mt = 0; mt < NMT; ++mt)
#pragma unroll
            for (int q = 0; q < 4; ++q) rm[mt * 4 + q] = fmaxf(rm[mt * 4 + q], fabsf(acc[mt][q]));
    }
#pragma unroll
    for (int i = 0; i < NMT * 4; ++i) {
        float m = rm[i];
        m = fmaxf(m, __shfl_xor(m, 1));
        m = fmaxf(m, __shfl_xor(m, 2));
        m = fmaxf(m, __shfl_xor(m, 4));
        m = fmaxf(m, __shfl_xor(m, 8));
        if (col == 0) atomicMax(&maxL[16 * (i >> 2) + 4 * g + (i & 3)], __float_as_uint(m));
    }
}

// ---------------- fused: amp GEMV (blocks 0..255) || convmax (blocks 256..2303) ----------------
__launch_bounds__(256)
__global__ void ampconv_kernel(const float* __restrict__ x,
                               const float* __restrict__ Wamp, const float* __restrict__ bamp,
                               float* __restrict__ ampT,
                               const float* __restrict__ noise,
                               const unsigned short* __restrict__ tapsA,
                               const float* __restrict__ swb,
                               const int* __restrict__ nmtb,
                               unsigned int* __restrict__ maxb) {
    int tid = threadIdx.x;
    __shared__ short tapsL[64 * 128];
    __shared__ short wsh[8][640];
    __shared__ float wf[640];
    __shared__ unsigned maxL[64];

    if (blockIdx.x < 256) {
        // ---- amp: amp = (x@W_amp+b)^2 -> ampT[b][fr][ch] ----
        int bq = blockIdx.x >> 6;          // 0..3 (8 b's each)
        int jt = blockIdx.x & 63;          // 256-wide j tile
        int j = jt * 256 + tid;
        float acc[8];
        float bj = bamp[j];
#pragma unroll
        for (int b = 0; b < 8; ++b) acc[b] = bj;
        const float* xb = x + bq * 8 * 128;
#pragma unroll 8
        for (int d = 0; d < 128; ++d) {
            float wv = Wamp[(size_t)d * 16384 + j];
#pragma unroll
            for (int b = 0; b < 8; ++b) acc[b] = fmaf(xb[b * 128 + d], wv, acc[b]);
        }
        int ch = j >> 7, fr = j & 127;
#pragma unroll
        for (int b = 0; b < 8; ++b) {
            float a = acc[b];
            ampT[(size_t)(bq * 8 + b) * 16384 + fr * 128 + ch] = a * a;
        }
        return;
    }

    // ---- convmax: 2048 blocks, b = bx>>6, tile = bx&63 ----
    int bx = blockIdx.x - 256;
    int b = bx >> 6;
    if (swb[b] == 0.0f) return;
    int nmt = nmtb[b];
    int T = (bx & 63) * 512;
    if (tid < 64) maxL[tid] = 0u;
    {
        const short8v* src = (const short8v*)(tapsA + ((size_t)b << 13));
        short8v* dst = (short8v*)tapsL;
        for (int i = tid; i < 1024; i += 256) dst[i] = src[i];
    }
    for (int i = tid; i < 640; i += 256)
        wf[i] = noise[(size_t)b * NSAMP + ((T - 127 + i) & NMASK)] * 2.0f - 1.0f;
    __syncthreads();
    for (int idx = tid; idx < 640; idx += 256) {
        int c = idx >> 3, s = idx & 7;
        short8v v;
#pragma unroll
        for (int e = 0; e < 8; ++e) {
            int t = 8 * c + e + s; t = t < 640 ? t : 639;
            v[e] = (short)f2bf(wf[t]);
        }
        *(short8v*)&wsh[s][8 * (c ^ s)] = v;
    }
    __syncthreads();
    switch (nmt) {
        case 1: convmax_core<1>(tid, tapsL, wsh, maxL); break;
        case 2: convmax_core<2>(tid, tapsL, wsh, maxL); break;
        case 3: convmax_core<3>(tid, tapsL, wsh, maxL); break;
        default: convmax_core<4>(tid, tapsL, wsh, maxL); break;
    }
    __syncthreads();
    if (tid < 64 && tid < nmt * 16) atomicMax(&maxb[b * 64 + tid], maxL[tid]);
}

// ---------------- final core ----------------
template<int NMT>
__device__ __forceinline__ void final_core(int b, int T, int tid, int s0, int shift,
                                           const short* tapsL, const short (*wsh)[640],
                                           const float4 (*seg)[64],
                                           const float (*ampA)[64], const float (*ampBn)[64],
                                           float* __restrict__ out) {
    int lane = tid & 63, w = tid >> 6;
    int g = lane >> 4, col = lane & 15, s_l = lane & 7, b3 = (lane >> 3) & 1;
    short8v fa[NMT][4];
#pragma unroll
    for (int mt = 0; mt < NMT; ++mt)
#pragma unroll
        for (int ks = 0; ks < 4; ++ks) {
            int row = 16 * mt + col;
            int ch = (4 * ks + g) ^ (row & 7);
            fa[mt][ks] = *(const short8v*)&tapsL[row * 128 + 8 * ch];
        }
    int dd = (w + 1) >> 1;                 // per-thread constant segment slot {0,1,1,2}
    bool head = (T + w * 128) < 128;       // only block 0, w==0
    float vsr[NMT * 4], dvr[NMT * 4], pbr[NMT * 4];
#pragma unroll
    for (int mt = 0; mt < NMT; ++mt)
#pragma unroll
        for (int q = 0; q < 4; ++q) {
            int i = mt * 4 + q, h = 16 * mt + 4 * g + q;
            float4 sgv = seg[dd][h];
            vsr[i] = sgv.x;
            dvr[i] = head ? 0.0f : sgv.y;
            pbr[i] = head ? (-128.0f * sgv.x) : sgv.z;   // head: p=(t+1)*v0 with m=t+129
        }
    // per-thread frame slot is ntl-invariant (128-sample span, T%512==0)
    int t_0 = T + w * 128 + col;
    int lo0 = (t_0 < 128) ? 0 : ((t_0 - 128) >> 8);
    int dlo = lo0 - s0;              // dhi = dlo+1 <= 3
    float loF = (float)lo0;
    f32x4 aloA[NMT], adA[NMT], aloB[NMT], adB[NMT];
#pragma unroll
    for (int mt = 0; mt < NMT; ++mt) {
        int h4 = 16 * mt + 4 * g;
        aloA[mt] = *(const f32x4*)&ampA[dlo][h4];
        adA[mt]  = *(const f32x4*)&ampA[dlo + 1][h4] - aloA[mt];
        aloB[mt] = *(const f32x4*)&ampBn[dlo][h4];
        adB[mt]  = *(const f32x4*)&ampBn[dlo + 1][h4] - aloB[mt];
    }

    for (int ntl = 0; ntl < 8; ++ntl) {
        int nt = w * 8 + ntl;
        short8v fb[4];
#pragma unroll
        for (int ks = 0; ks < 4; ++ks) {
            int t0 = 120 + 16 * nt - 32 * ks - 8 * g + 8 * b3;
            int ch = (t0 >> 3) ^ s_l;
            fb[ks] = *(const short8v*)&wsh[s_l][8 * ch];
        }
        f32x4 acc[NMT];
#pragma unroll
        for (int mt = 0; mt < NMT; ++mt) acc[mt] = (f32x4){0, 0, 0, 0};
#pragma unroll
        for (int ks = 0; ks < 4; ++ks)
#pragma unroll
            for (int mt = 0; mt < NMT; ++mt)
                acc[mt] = __builtin_amdgcn_mfma_f32_16x16x32_bf16(fa[mt][ks], fb[ks], acc[mt], 0, 0, 0);

        int j = w * 128 + ntl * 16 + col;
        int t = T + j;
        float coords = ((float)t + 0.5f) * (1.0f / 256.0f) - 0.5f;
        coords = fminf(fmaxf(coords, 0.0f), 127.0f);
        float w1 = coords - loF;
        float mp1 = (float)(((t - 128) & 255) + 1);
        float mp2 = mp1 * mp1;
        float psum = 0.0f;
#pragma unroll
        for (int mt = 0; mt < NMT; ++mt) {
#pragma unroll
            for (int q = 0; q < 4; ++q) {
                int i = mt * 4 + q;
                float p = fmaf(mp2, dvr[i], fmaf(mp1, vsr[i], pbr[i]));
                p -= floorf(p);
                float sv = sinrev(p);
                float aA = fmaf(w1, adA[mt][q], aloA[mt][q]);
                float aB = fmaf(w1, adB[mt][q], aloB[mt][q]);
                psum = fmaf(sv, aA, psum);
                psum = fmaf(acc[mt][q], aB, psum);
            }
        }
        // cross-g reduction is intra-wave (g = lane>>4): butterfly, then lanes 0-15
        // (g==0) hold the full 64-h sum for sample j and store directly.
        psum += __shfl_xor(psum, 16);
        psum += __shfl_xor(psum, 32);
        if (lane < 16) {
            int pos = (T + j + shift) & NMASK;   // shift % 256 == 0: 16-dword run never wraps
            out[(size_t)b * NSAMP + pos] = psum;
        }
    }
}

// ---------------- pass 2: fused MFMA conv + revolutions sine + reg-hoisted amp lerp ----
__launch_bounds__(256)
__global__ void final_kernel(const float* __restrict__ noise,
                             const unsigned short* __restrict__ tapsA,
                             const float* __restrict__ PmodR, const float* __restrict__ vfreq,
                             const float* __restrict__ ampT,
                             const unsigned int* __restrict__ maxb,
                             const float* __restrict__ swb, const int* __restrict__ shiftb,
                             const int* __restrict__ nmtb,
                             float* __restrict__ out) {
    int b = blockIdx.y;
    int T = blockIdx.x * 512, tid = threadIdx.x;
    if (swb[b] == 0.0f) {
        out[(size_t)b * NSAMP + T + tid] = 0.0f;
        out[(size_t)b * NSAMP + T + 256 + tid] = 0.0f;
        return;
    }
    int nmt = nmtb[b];
    __shared__ short tapsL[64 * 128];
    __shared__ short wsh[8][640];
    __shared__ float wf[640];
    __shared__ float4 seg[3][64];     // (vs_rev, dv_rev, Pb_rev, -) per (segment-slot, h)
    __shared__ float ampA[4][64], ampBn[4][64];  // SoA, invn folded into B

    int s0 = (T >> 8) - 1;
    // ---- phase A: global loads ----
    for (int i = tid; i < 640; i += 256)
        wf[i] = noise[(size_t)b * NSAMP + ((T - 127 + i) & NMASK)] * 2.0f - 1.0f;
    {
        const short8v* src = (const short8v*)(tapsA + ((size_t)b << 13));
        short8v* dst = (short8v*)tapsL;
        for (int i = tid; i < 1024; i += 256) dst[i] = src[i];
    }
    {
        int ad = tid >> 6, ah = tid & 63;
        int afr = min(max(s0 + ad, 0), 127);
        float aAv = ampT[(size_t)b * 16384 + afr * 128 + ah];
        float aBv = ampT[(size_t)b * 16384 + afr * 128 + 64 + ah];
        float invn = 1.0f / (__uint_as_float(maxb[b * 64 + ah]) + 1e-8f);
        ampA[ad][ah] = aAv;
        ampBn[ad][ah] = aBv * invn;
    }
    if (tid < 192) {
        int dd = tid >> 6, h2 = tid & 63;
        size_t vb = ((size_t)(b * 64 + h2)) * 128;
        int s = min(max(s0 + dd, 0), 127), s1 = min(s + 1, 127);
        float vs = vfreq[vb + s], vs1 = vfreq[vb + s1];
        float4 sgv;
        sgv.x = vs;
        sgv.y = (vs1 - vs) * (1.0f / 512.0f);
        sgv.z = PmodR[vb + s];
        sgv.w = 0.0f;
        seg[dd][h2] = sgv;
    }
    __syncthreads();
    // ---- phase B: wsh build (reads wf), then cores read tapsL/wsh/seg/amp ----
    for (int idx = tid; idx < 640; idx += 256) {
        int c = idx >> 3, s = idx & 7;
        short8v v;
#pragma unroll
        for (int e = 0; e < 8; ++e) {
            int t = 8 * c + e + s; t = t < 640 ? t : 639;
            v[e] = (short)f2bf(wf[t]);
        }
        *(short8v*)&wsh[s][8 * (c ^ s)] = v;
    }
    __syncthreads();
    int shift = shiftb[b];
    switch (nmt) {
        case 1: final_core<1>(b, T, tid, s0, shift, tapsL, wsh, seg, ampA, ampBn, out); break;
        case 2: final_core<2>(b, T, tid, s0, shift, tapsL, wsh, seg, ampA, ampBn, out); break;
        case 3: final_core<3>(b, T, tid, s0, shift, tapsL, wsh, seg, ampA, ampBn, out); break;
        default: final_core<4>(b, T, tid, s0, shift, tapsL, wsh, seg, ampA, ampBn, out); break;
    }
}

extern "C" void kernel_launch(void* const* d_in, const int* in_sizes, int n_in,
                              void* d_out, int out_size, void* d_ws, size_t ws_size,
                              hipStream_t stream) {
    const float* x     = (const float*)d_in[0];
    const float* Wsw   = (const float*)d_in[1];
    const float* bsw   = (const float*)d_in[2];
    const float* Wf0   = (const float*)d_in[3];
    const float* bf0   = (const float*)d_in[4];
    const float* Wfv   = (const float*)d_in[5];
    const float* bfv   = (const float*)d_in[6];
    const float* Wamp  = (const float*)d_in[7];
    const float* bamp  = (const float*)d_in[8];
    const float* Wloc  = (const float*)d_in[9];
    const float* bloc  = (const float*)d_in[10];
    const float* usw   = (const float*)d_in[11];
    const float* uloc  = (const float*)d_in[12];
    const float* noise = (const float*)d_in[13];

    char* ws = (char*)d_ws;
    float*    PmodR  = (float*)(ws + OFF_PM);
    float*    vfreq  = (float*)(ws + OFF_V);
    unsigned short* tapsA = (unsigned short*)(ws + OFF_TA);
    float*    ampT   = (float*)(ws + OFF_A);
    unsigned* maxb   = (unsigned*)(ws + OFF_M);
    float*    swb    = (float*)(ws + OFF_SW);
    int*      shiftb = (int*)(ws + OFF_SH);
    int*      nmtb   = (int*)(ws + OFF_NM);
    float*    out    = (float*)d_out;

    prep_kernel<<<dim3(32), 256, 0, stream>>>(x, Wsw, bsw, Wf0, bf0, Wfv, bfv, Wloc, bloc,
                                              usw, uloc, PmodR, vfreq, tapsA, swb, shiftb,
                                              maxb, nmtb);
    ampconv_kernel<<<dim3(2304), 256, 0, stream>>>(x, Wamp, bamp, ampT, noise, tapsA,
                                                   swb, nmtb, maxb);
    final_kernel<<<dim3(64, 32), 256, 0, stream>>>(noise, tapsA, PmodR, vfreq, ampT, maxb,
                                                   swb, shiftb, nmtb, out);
}

// Round 12
// 54.177 us; speedup vs baseline: 1.0040x; 1.0040x over previous
//
#include <hip/hip_runtime.h>
#include <math.h>

typedef __attribute__((ext_vector_type(8))) short short8v;   // 8 bf16 (4 VGPRs)
typedef __attribute__((ext_vector_type(4))) float f32x4;

namespace {
constexpr int NSAMP = 32768;
constexpr int NMASK = NSAMP - 1;
constexpr float MIN_F_F = (float)(30.0 / 11025.0);
constexpr float SPAN_F  = (float)(3000.0 / 11025.0 - 30.0 / 11025.0);
constexpr float PI_F    = 3.14159265358979323846f;
constexpr double TWO_PI  = 6.283185307179586476925287;
constexpr double INV_2PI = 0.159154943091895335768884;
constexpr float INV_2PI_F = 0.15915494309189533577f;
constexpr float INV_SQRT_N = 0.00552427172801990295f; // 1/sqrt(32768)

// ws layout (bytes)
constexpr size_t OFF_PM = 0;                          // float PmodR [32][64][128]  1 MB
constexpr size_t OFF_V  = OFF_PM + 32*64*128*4;       // float vfreq [32][64][128]  1 MB
constexpr size_t OFF_TA = OFF_V  + 32*64*128*4;       // u16   tapsA [32][64][128]  512 KB
constexpr size_t OFF_A  = OFF_TA + 32*64*128*2;       // float ampT  [32][128fr][128ch] 2 MB
constexpr size_t OFF_M  = OFF_A  + 32*128*128*4;      // uint  maxb  [2048]
constexpr size_t OFF_SW = OFF_M  + 2048*4;            // float swb   [32]
constexpr size_t OFF_SH = OFF_SW + 32*4;              // int   shiftb[32]
constexpr size_t OFF_NM = OFF_SH + 32*4;              // int   nmtb  [32] (active 16-h blocks)
}

__device__ __forceinline__ float sigmoidf_(float z) { return 1.0f / (1.0f + expf(-z)); }
__device__ __forceinline__ float gumbelf_(float u) { return -logf(-logf(u + 1e-10f) + 1e-10f); }
__device__ __forceinline__ unsigned short f2bf(float f) {
    unsigned u = __float_as_uint(f);
    return (unsigned short)((u + 0x7FFFu + ((u >> 16) & 1u)) >> 16);
}
__device__ __forceinline__ float sinrev(float r) {   // r in [0,1): sin(2*pi*r)
#if __has_builtin(__builtin_amdgcn_sinf)
    return __builtin_amdgcn_sinf(r);
#else
    return __sinf(r * 6.2831853071795864769f);
#endif
}

// ---------------- setup: amp GEMV (blocks 0..255) || prep (blocks 256..287) ----------------
__launch_bounds__(256)
__global__ void setup_kernel(const float* __restrict__ x,
                             const float* __restrict__ Wsw, const float* __restrict__ bsw,
                             const float* __restrict__ Wf0, const float* __restrict__ bf0,
                             const float* __restrict__ Wfv, const float* __restrict__ bfv,
                             const float* __restrict__ Wamp, const float* __restrict__ bamp,
                             const float* __restrict__ Wloc, const float* __restrict__ bloc,
                             const float* __restrict__ usw, const float* __restrict__ uloc,
                             float* __restrict__ ampT,
                             float* __restrict__ PmodR, float* __restrict__ vfreq,
                             unsigned short* __restrict__ tapsA, float* __restrict__ swb,
                             int* __restrict__ shiftb, unsigned int* __restrict__ maxb,
                             int* __restrict__ nmtb) {
    int tid = threadIdx.x;
    __shared__ float xs[128], f0t[128];
    __shared__ float redA[128]; __shared__ int redI[128];
    __shared__ float red0[128], red1[128], red2[128];
    __shared__ int maxHsh;

    if (blockIdx.x < 256) {
        // ---- amp part: amp = (x@W_amp+b)^2 -> ampT[b][fr][ch] ----
        int bq = blockIdx.x >> 6;          // 0..3 (8 b's each)
        int jt = blockIdx.x & 63;          // 256-wide j tile
        int j = jt * 256 + tid;
        float acc[8];
        float bj = bamp[j];
#pragma unroll
        for (int b = 0; b < 8; ++b) acc[b] = bj;
        const float* xb = x + bq * 8 * 128;
#pragma unroll 8
        for (int d = 0; d < 128; ++d) {
            float wv = Wamp[(size_t)d * 16384 + j];
#pragma unroll
            for (int b = 0; b < 8; ++b) acc[b] = fmaf(xb[b * 128 + d], wv, acc[b]);
        }
        int ch = j >> 7, fr = j & 127;
#pragma unroll
        for (int b = 0; b < 8; ++b) {
            float a = acc[b];
            ampT[(size_t)(bq * 8 + b) * 16384 + fr * 128 + ch] = a * a;
        }
        return;
    }

    // ---- prep part: one block per b ----
    int b = blockIdx.x - 256;
    if (tid < 64) maxb[b * 64 + tid] = 0u;
    if (tid == 0) maxHsh = 0;
    if (tid < 128) xs[tid] = x[b * 128 + tid];
    __syncthreads();

    // per-frame dots: threads 0..127 -> f0_var logits; 128..255 -> loc logits
    {
        int half = tid >> 7, fr = tid & 127;
        const float* W = half ? Wloc : Wfv;
        float a = (half ? bloc : bfv)[fr];
        for (int d = 0; d < 128; ++d) a = fmaf(xs[d], W[d * 128 + fr], a);
        if (half) { redA[fr] = sigmoidf_(a) + gumbelf_(uloc[b * 128 + fr]); redI[fr] = fr; }
        else      { f0t[fr] = sigmoidf_(a) * 2.0f - 1.0f; }   // f0var stash
    }
    if (tid < 128) {
        red0[tid] = xs[tid] * Wsw[tid * 2 + 0];
        red1[tid] = xs[tid] * Wsw[tid * 2 + 1];
        red2[tid] = xs[tid] * Wf0[tid];
    }
    __syncthreads();
    for (int off = 64; off > 0; off >>= 1) {
        if (tid < off) {
            red0[tid] += red0[tid + off];
            red1[tid] += red1[tid + off];
            red2[tid] += red2[tid + off];
            if (redA[tid + off] > redA[tid]) { redA[tid] = redA[tid + off]; redI[tid] = redI[tid + off]; }
        }
        __syncthreads();
    }
    float l0 = red0[0] + bsw[0], l1 = red1[0] + bsw[1];
    float g0 = gumbelf_(usw[b * 2 + 0]), g1 = gumbelf_(usw[b * 2 + 1]);
    float swv = (l0 + g0 >= l1 + g1) ? 1.0f : 0.0f;
    float sg = sigmoidf_(red2[0] + bf0[0]);
    float f0v = MIN_F_F + (sg * sg) * SPAN_F;
    if (tid == 0) { swb[b] = swv; shiftb[b] = redI[0] * 256; }
    if (tid < 128) {
        float f0var = f0t[tid];
        f0t[tid] = f0v + f0var * (f0v * 0.01f);
    }
    __syncthreads();

    // phase-prefix scan + taps, 4 waves x 16 h each; lane handles k=2l,2l+1
    int wave = tid >> 6, lane = tid & 63;
    int k0 = lane * 2, k1 = k0 + 1;
    int myMaxH = 0;
    for (int h = wave; h < 64; h += 4) {
        float hf = (float)(h + 1);
        size_t base = ((size_t)b * 64 + h) * 128;
        float vA = f0t[k0] * hf; vA = (vA > 1.0f) ? 0.0f : vA * PI_F;
        float vB = f0t[k1] * hf; vB = (vB > 1.0f) ? 0.0f : vB * PI_F;
        if (__any((vA > 0.0f) || (vB > 0.0f))) myMaxH = h;   // activity monotone in h
        double v0d = (double)vA, v1d = (double)vB;
        double sc = v0d + v1d;
#pragma unroll
        for (int d = 1; d < 64; d <<= 1) {
            double o = __shfl_up(sc, d);
            if (lane >= d) sc += o;
        }
        // P(k) = 128*(2*S(k) - v[k]); S(2l+1)=sc, S(2l)=sc-v1
        double P0 = 128.0 * (2.0 * sc - 2.0 * v1d - v0d);
        double P1 = 128.0 * (2.0 * sc - v1d);
        double r0 = P0 * INV_2PI; r0 -= floor(r0);
        double r1 = P1 * INV_2PI; r1 -= floor(r1);
        PmodR[base + k0] = (float)r0;
        PmodR[base + k1] = (float)r1;
        vfreq[base + k0] = vA * INV_2PI_F;
        vfreq[base + k1] = vB * INV_2PI_F;
        // taps (depend only on v0 of this h)
        float v0_rad = __shfl(vA, 0);
        double v0rev = (double)v0_rad * INV_2PI;
#pragma unroll
        for (int kk = 0; kk < 2; ++kk) {
            int k = k0 + kk;
            float hwk = 0.54f - 0.46f * cosf(6.2831853071795864769f * (float)k / 128.0f);
            double rv = (double)(k + 1) * v0rev; rv -= floor(rv);
            float sv = __sinf((float)(rv * TWO_PI));
            float tv = sv * hwk * INV_SQRT_N;
            int c = k >> 3, e = 7 - (k & 7);
            tapsA[base + 8 * (c ^ (h & 7)) + e] = f2bf(tv);
        }
    }
    if (lane == 0) atomicMax(&maxHsh, myMaxH);
    __syncthreads();
    if (tid == 0) nmtb[b] = (maxHsh >> 4) + 1;
}

// Conv core notes:
//   k-fill convention (same for A and B, so any HW k-permutation cancels):
//     frag[r] corresponds to logical k = 32*ks + 8*(lane>>4) + (7 - r)
//   A (taps) stored pre-reversed -> one aligned b128 per (mt,ks)
//   B: wsh[s][t] = w[t+s], chunk c stored at c^s -> one aligned, conflict-free b128
//   Dead-harmonic skip: COMPILE-TIME via template<NMT> + uniform switch (R8 lesson).
//   R11 lesson: kernel VGPR = max over instantiations -> split final into lo (NMT<=2,
//   low-reg, ~75% of b's) and hi (NMT>=3) KERNELS so common case gets 4 waves/SIMD.

// ---------------- pass 1 core ----------------
template<int NMT>
__device__ __forceinline__ void convmax_core(int tid, const short* tapsL,
                                             const short (*wsh)[640],
                                             unsigned int* maxL) {
    int lane = tid & 63, w = tid >> 6;
    int g = lane >> 4, col = lane & 15, s_l = lane & 7, b3 = (lane >> 3) & 1;
    short8v fa[NMT][4];
#pragma unroll
    for (int mt = 0; mt < NMT; ++mt)
#pragma unroll
        for (int ks = 0; ks < 4; ++ks) {
            int row = 16 * mt + col;
            int ch = (4 * ks + g) ^ (row & 7);
            fa[mt][ks] = *(const short8v*)&tapsL[row * 128 + 8 * ch];
        }
    float rm[NMT * 4];
#pragma unroll
    for (int i = 0; i < NMT * 4; ++i) rm[i] = 0.0f;
    for (int ntl = 0; ntl < 8; ++ntl) {
        int nt = w * 8 + ntl;
        short8v fb[4];
#pragma unroll
        for (int ks = 0; ks < 4; ++ks) {
            int t0 = 120 + 16 * nt - 32 * ks - 8 * g + 8 * b3;
            int ch = (t0 >> 3) ^ s_l;
            fb[ks] = *(const short8v*)&wsh[s_l][8 * ch];
        }
        f32x4 acc[NMT];
#pragma unroll
        for (int mt = 0; mt < NMT; ++mt) acc[mt] = (f32x4){0, 0, 0, 0};
#pragma unroll
        for (int ks = 0; ks < 4; ++ks)
#pragma unroll
            for (int mt = 0; mt < NMT; ++mt)
                acc[mt] = __builtin_amdgcn_mfma_f32_16x16x32_bf16(fa[mt][ks], fb[ks], acc[mt], 0, 0, 0);
#pragma unroll
        for (int mt = 0; mt < NMT; ++mt)
#pragma unroll
            for (int q = 0; q < 4; ++q) rm[mt * 4 + q] = fmaxf(rm[mt * 4 + q], fabsf(acc[mt][q]));
    }
#pragma unroll
    for (int i = 0; i < NMT * 4; ++i) {
        float m = rm[i];
        m = fmaxf(m, __shfl_xor(m, 1));
        m = fmaxf(m, __shfl_xor(m, 2));
        m = fmaxf(m, __shfl_xor(m, 4));
        m = fmaxf(m, __shfl_xor(m, 8));
        if (col == 0) atomicMax(&maxL[16 * (i >> 2) + 4 * g + (i & 3)], __float_as_uint(m));
    }
}

// ---------------- pass 1: MFMA circular FIR, 1 tile/block, per-(b,h) row max ----
__launch_bounds__(256)
__global__ void convmax_kernel(const float* __restrict__ noise,
                               const unsigned short* __restrict__ tapsA,
                               const float* __restrict__ swb,
                               const int* __restrict__ nmtb,
                               unsigned int* __restrict__ maxb) {
    int b = blockIdx.y;
    if (swb[b] == 0.0f) return;
    int nmt = nmtb[b];
    int tid = threadIdx.x;
    int T = blockIdx.x * 512;
    __shared__ short tapsL[64 * 128];
    __shared__ short wsh[8][640];
    __shared__ float wf[640];
    __shared__ unsigned maxL[64];
    if (tid < 64) maxL[tid] = 0u;
    {
        const short8v* src = (const short8v*)(tapsA + ((size_t)b << 13));
        short8v* dst = (short8v*)tapsL;
        for (int i = tid; i < 1024; i += 256) dst[i] = src[i];
    }
    for (int i = tid; i < 640; i += 256)
        wf[i] = noise[(size_t)b * NSAMP + ((T - 127 + i) & NMASK)] * 2.0f - 1.0f;
    __syncthreads();
    for (int idx = tid; idx < 640; idx += 256) {
        int c = idx >> 3, s = idx & 7;
        short8v v;
#pragma unroll
        for (int e = 0; e < 8; ++e) {
            int t = 8 * c + e + s; t = t < 640 ? t : 639;
            v[e] = (short)f2bf(wf[t]);
        }
        *(short8v*)&wsh[s][8 * (c ^ s)] = v;
    }
    __syncthreads();
    switch (nmt) {
        case 1: convmax_core<1>(tid, tapsL, wsh, maxL); break;
        case 2: convmax_core<2>(tid, tapsL, wsh, maxL); break;
        case 3: convmax_core<3>(tid, tapsL, wsh, maxL); break;
        default: convmax_core<4>(tid, tapsL, wsh, maxL); break;
    }
    __syncthreads();
    if (tid < 64 && tid < nmt * 16) atomicMax(&maxb[b * 64 + tid], maxL[tid]);
}

// ---------------- pass 2 core ----------------
template<int NMT>
__device__ __forceinline__ void final_core(int b, int T, int tid, int s0, int shift,
                                           const short* tapsL, const short (*wsh)[640],
                                           const float4 (*seg)[64],
                                           const float (*ampA)[64], const float (*ampBn)[64],
                                           float (*part)[520], float* __restrict__ out) {
    int lane = tid & 63, w = tid >> 6;
    int g = lane >> 4, col = lane & 15, s_l = lane & 7, b3 = (lane >> 3) & 1;
    short8v fa[NMT][4];
#pragma unroll
    for (int mt = 0; mt < NMT; ++mt)
#pragma unroll
        for (int ks = 0; ks < 4; ++ks) {
            int row = 16 * mt + col;
            int ch = (4 * ks + g) ^ (row & 7);
            fa[mt][ks] = *(const short8v*)&tapsL[row * 128 + 8 * ch];
        }
    int dd = (w + 1) >> 1;                 // per-thread constant segment slot {0,1,1,2}
    bool head = (T + w * 128) < 128;       // only block 0, w==0
    float vsr[NMT * 4], dvr[NMT * 4], pbr[NMT * 4];
#pragma unroll
    for (int mt = 0; mt < NMT; ++mt)
#pragma unroll
        for (int q = 0; q < 4; ++q) {
            int i = mt * 4 + q, h = 16 * mt + 4 * g + q;
            float4 sgv = seg[dd][h];
            vsr[i] = sgv.x;
            dvr[i] = head ? 0.0f : sgv.y;
            pbr[i] = head ? (-128.0f * sgv.x) : sgv.z;   // head: p=(t+1)*v0 with m=t+129
        }
    // per-thread frame slot is ntl-invariant (128-sample span, T%512==0)
    int t_0 = T + w * 128 + col;
    int lo0 = (t_0 < 128) ? 0 : ((t_0 - 128) >> 8);
    int dlo = lo0 - s0;              // dhi = dlo+1 <= 3
    float loF = (float)lo0;
    f32x4 aloA[NMT], adA[NMT], aloB[NMT], adB[NMT];
#pragma unroll
    for (int mt = 0; mt < NMT; ++mt) {
        int h4 = 16 * mt + 4 * g;
        aloA[mt] = *(const f32x4*)&ampA[dlo][h4];
        adA[mt]  = *(const f32x4*)&ampA[dlo + 1][h4] - aloA[mt];
        aloB[mt] = *(const f32x4*)&ampBn[dlo][h4];
        adB[mt]  = *(const f32x4*)&ampBn[dlo + 1][h4] - aloB[mt];
    }
    __syncthreads();

    for (int ntl = 0; ntl < 8; ++ntl) {
        int nt = w * 8 + ntl;
        short8v fb[4];
#pragma unroll
        for (int ks = 0; ks < 4; ++ks) {
            int t0 = 120 + 16 * nt - 32 * ks - 8 * g + 8 * b3;
            int ch = (t0 >> 3) ^ s_l;
            fb[ks] = *(const short8v*)&wsh[s_l][8 * ch];
        }
        f32x4 acc[NMT];
#pragma unroll
        for (int mt = 0; mt < NMT; ++mt) acc[mt] = (f32x4){0, 0, 0, 0};
#pragma unroll
        for (int ks = 0; ks < 4; ++ks)
#pragma unroll
            for (int mt = 0; mt < NMT; ++mt)
                acc[mt] = __builtin_amdgcn_mfma_f32_16x16x32_bf16(fa[mt][ks], fb[ks], acc[mt], 0, 0, 0);

        int j = w * 128 + ntl * 16 + col;
        int t = T + j;
        float coords = ((float)t + 0.5f) * (1.0f / 256.0f) - 0.5f;
        coords = fminf(fmaxf(coords, 0.0f), 127.0f);
        float w1 = coords - loF;
        float mp1 = (float)(((t - 128) & 255) + 1);
        float mp2 = mp1 * mp1;
        float psum = 0.0f;
#pragma unroll
        for (int mt = 0; mt < NMT; ++mt) {
#pragma unroll
            for (int q = 0; q < 4; ++q) {
                int i = mt * 4 + q;
                float p = fmaf(mp2, dvr[i], fmaf(mp1, vsr[i], pbr[i]));
                p -= floorf(p);
                float sv = sinrev(p);
                float aA = fmaf(w1, adA[mt][q], aloA[mt][q]);
                float aB = fmaf(w1, adB[mt][q], aloB[mt][q]);
                psum = fmaf(sv, aA, psum);
                psum = fmaf(acc[mt][q], aB, psum);
            }
        }
        part[g][j] = psum;
    }
    __syncthreads();
#pragma unroll
    for (int rep = 0; rep < 2; ++rep) {
        int j2 = rep * 256 + tid;
        float r = part[0][j2] + part[1][j2] + part[2][j2] + part[3][j2];
        int pos = (T + j2 + shift) & NMASK;
        out[(size_t)b * NSAMP + pos] = r;
    }
}

// Shared staging for both final kernels (identical bodies except the nmt gate + switch)
#define FINAL_STAGE()                                                                     \
    int s0 = (T >> 8) - 1;                                                                \
    for (int i = tid; i < 640; i += 256)                                                  \
        wf[i] = noise[(size_t)b * NSAMP + ((T - 127 + i) & NMASK)] * 2.0f - 1.0f;         \
    {                                                                                     \
        const short8v* src = (const short8v*)(tapsA + ((size_t)b << 13));                 \
        short8v* dst = (short8v*)R.tapsL;                                                 \
        for (int i = tid; i < 1024; i += 256) dst[i] = src[i];                            \
    }                                                                                     \
    {                                                                                     \
        int ad = tid >> 6, ah = tid & 63;                                                 \
        int afr = min(max(s0 + ad, 0), 127);                                              \
        float aAv = ampT[(size_t)b * 16384 + afr * 128 + ah];                             \
        float aBv = ampT[(size_t)b * 16384 + afr * 128 + 64 + ah];                        \
        float invn = 1.0f / (__uint_as_float(maxb[b * 64 + ah]) + 1e-8f);                 \
        ampA[ad][ah] = aAv;                                                               \
        ampBn[ad][ah] = aBv * invn;                                                       \
    }                                                                                     \
    if (tid < 192) {                                                                      \
        int dd = tid >> 6, h2 = tid & 63;                                                 \
        size_t vb = ((size_t)(b * 64 + h2)) * 128;                                        \
        int s = min(max(s0 + dd, 0), 127), s1 = min(s + 1, 127);                          \
        float vs = vfreq[vb + s], vs1 = vfreq[vb + s1];                                   \
        float4 sgv;                                                                       \
        sgv.x = vs;                                                                       \
        sgv.y = (vs1 - vs) * (1.0f / 512.0f);                                             \
        sgv.z = PmodR[vb + s];                                                            \
        sgv.w = 0.0f;                                                                     \
        seg[dd][h2] = sgv;                                                                \
    }                                                                                     \
    __syncthreads();                                                                      \
    for (int idx = tid; idx < 640; idx += 256) {                                          \
        int c = idx >> 3, s = idx & 7;                                                    \
        short8v v;                                                                        \
        for (int e = 0; e < 8; ++e) {                                                     \
            int t = 8 * c + e + s; t = t < 640 ? t : 639;                                 \
            v[e] = (short)f2bf(wf[t]);                                                    \
        }                                                                                 \
        *(short8v*)&wsh[s][8 * (c ^ s)] = v;                                              \
    }

// ---------------- pass 2a: common case, nmt<=2 (low VGPR -> 4 waves/SIMD) ----------------
__launch_bounds__(256)
__global__ void final_lo_kernel(const float* __restrict__ noise,
                                const unsigned short* __restrict__ tapsA,
                                const float* __restrict__ PmodR, const float* __restrict__ vfreq,
                                const float* __restrict__ ampT,
                                const unsigned int* __restrict__ maxb,
                                const float* __restrict__ swb, const int* __restrict__ shiftb,
                                const int* __restrict__ nmtb,
                                float* __restrict__ out) {
    int b = blockIdx.y;
    int T = blockIdx.x * 512, tid = threadIdx.x;
    if (swb[b] == 0.0f) {
        out[(size_t)b * NSAMP + T + tid] = 0.0f;
        out[(size_t)b * NSAMP + T + 256 + tid] = 0.0f;
        return;
    }
    int nmt = nmtb[b];
    if (nmt > 2) return;   // final_hi handles
    __shared__ union { short tapsL[64 * 128]; float part[4][520]; } R;
    __shared__ short wsh[8][640];
    __shared__ float wf[640];
    __shared__ float4 seg[3][64];
    __shared__ float ampA[4][64], ampBn[4][64];
    FINAL_STAGE()
    int shift = shiftb[b];
    if (nmt == 1) final_core<1>(b, T, tid, s0, shift, R.tapsL, wsh, seg, ampA, ampBn, R.part, out);
    else          final_core<2>(b, T, tid, s0, shift, R.tapsL, wsh, seg, ampA, ampBn, R.part, out);
}

// ---------------- pass 2b: rare case, nmt>=3 ----------------
__launch_bounds__(256)
__global__ void final_hi_kernel(const float* __restrict__ noise,
                                const unsigned short* __restrict__ tapsA,
                                const float* __restrict__ PmodR, const float* __restrict__ vfreq,
                                const float* __restrict__ ampT,
                                const unsigned int* __restrict__ maxb,
                                const float* __restrict__ swb, const int* __restrict__ shiftb,
                                const int* __restrict__ nmtb,
                                float* __restrict__ out) {
    int b = blockIdx.y;
    int T = blockIdx.x * 512, tid = threadIdx.x;
    if (swb[b] == 0.0f) return;
    int nmt = nmtb[b];
    if (nmt < 3) return;   // final_lo handled
    __shared__ union { short tapsL[64 * 128]; float part[4][520]; } R;
    __shared__ short wsh[8][640];
    __shared__ float wf[640];
    __shared__ float4 seg[3][64];
    __shared__ float ampA[4][64], ampBn[4][64];
    FINAL_STAGE()
    int shift = shiftb[b];
    if (nmt == 3) final_core<3>(b, T, tid, s0, shift, R.tapsL, wsh, seg, ampA, ampBn, R.part, out);
    else          final_core<4>(b, T, tid, s0, shift, R.tapsL, wsh, seg, ampA, ampBn, R.part, out);
}

extern "C" void kernel_launch(void* const* d_in, const int* in_sizes, int n_in,
                              void* d_out, int out_size, void* d_ws, size_t ws_size,
                              hipStream_t stream) {
    const float* x     = (const float*)d_in[0];
    const float* Wsw   = (const float*)d_in[1];
    const float* bsw   = (const float*)d_in[2];
    const float* Wf0   = (const float*)d_in[3];
    const float* bf0   = (const float*)d_in[4];
    const float* Wfv   = (const float*)d_in[5];
    const float* bfv   = (const float*)d_in[6];
    const float* Wamp  = (const float*)d_in[7];
    const float* bamp  = (const float*)d_in[8];
    const float* Wloc  = (const float*)d_in[9];
    const float* bloc  = (const float*)d_in[10];
    const float* usw   = (const float*)d_in[11];
    const float* uloc  = (const float*)d_in[12];
    const float* noise = (const float*)d_in[13];

    char* ws = (char*)d_ws;
    float*    PmodR  = (float*)(ws + OFF_PM);
    float*    vfreq  = (float*)(ws + OFF_V);
    unsigned short* tapsA = (unsigned short*)(ws + OFF_TA);
    float*    ampT   = (float*)(ws + OFF_A);
    unsigned* maxb   = (unsigned*)(ws + OFF_M);
    float*    swb    = (float*)(ws + OFF_SW);
    int*      shiftb = (int*)(ws + OFF_SH);
    int*      nmtb   = (int*)(ws + OFF_NM);
    float*    out    = (float*)d_out;

    setup_kernel<<<dim3(288), 256, 0, stream>>>(x, Wsw, bsw, Wf0, bf0, Wfv, bfv, Wamp, bamp,
                                                Wloc, bloc, usw, uloc, ampT,
                                                PmodR, vfreq, tapsA, swb, shiftb, maxb, nmtb);
    convmax_kernel<<<dim3(64, 32), 256, 0, stream>>>(noise, tapsA, swb, nmtb, maxb);
    final_lo_kernel<<<dim3(64, 32), 256, 0, stream>>>(noise, tapsA, PmodR, vfreq, ampT, maxb,
                                                      swb, shiftb, nmtb, out);
    final_hi_kernel<<<dim3(64, 32), 256, 0, stream>>>(noise, tapsA, PmodR, vfreq, ampT, maxb,
                                                      swb, shiftb, nmtb, out);
}

// Round 13
// 50.118 us; speedup vs baseline: 1.0854x; 1.0810x over previous
//
#include <hip/hip_runtime.h>
#include <math.h>

typedef __attribute__((ext_vector_type(8))) short short8v;   // 8 bf16 (4 VGPRs)
typedef __attribute__((ext_vector_type(4))) float f32x4;

namespace {
constexpr int NSAMP = 32768;
constexpr int NMASK = NSAMP - 1;
constexpr float MIN_F_F = (float)(30.0 / 11025.0);
constexpr float SPAN_F  = (float)(3000.0 / 11025.0 - 30.0 / 11025.0);
constexpr float PI_F    = 3.14159265358979323846f;
constexpr double TWO_PI  = 6.283185307179586476925287;
constexpr double INV_2PI = 0.159154943091895335768884;
constexpr float INV_2PI_F = 0.15915494309189533577f;
constexpr float INV_SQRT_N = 0.00552427172801990295f; // 1/sqrt(32768)

// ws layout (bytes)
constexpr size_t OFF_PM = 0;                          // float PmodR [32][64][128]  1 MB
constexpr size_t OFF_V  = OFF_PM + 32*64*128*4;       // float vfreq [32][64][128]  1 MB
constexpr size_t OFF_TA = OFF_V  + 32*64*128*4;       // u16   tapsA [32][64][128]  512 KB
constexpr size_t OFF_A  = OFF_TA + 32*64*128*2;       // float ampT  [32][128fr][128ch] 2 MB
constexpr size_t OFF_M  = OFF_A  + 32*128*128*4;      // uint  maxb  [2048]
constexpr size_t OFF_SW = OFF_M  + 2048*4;            // float swb   [32]
constexpr size_t OFF_SH = OFF_SW + 32*4;              // int   shiftb[32]
constexpr size_t OFF_NM = OFF_SH + 32*4;              // int   nmtb  [32] (active 16-h blocks)
}

__device__ __forceinline__ float sigmoidf_(float z) { return 1.0f / (1.0f + expf(-z)); }
__device__ __forceinline__ float gumbelf_(float u) { return -logf(-logf(u + 1e-10f) + 1e-10f); }
__device__ __forceinline__ unsigned short f2bf(float f) {
    unsigned u = __float_as_uint(f);
    return (unsigned short)((u + 0x7FFFu + ((u >> 16) & 1u)) >> 16);
}
__device__ __forceinline__ float sinrev(float r) {   // r in [0,1): sin(2*pi*r)
#if __has_builtin(__builtin_amdgcn_sinf)
    return __builtin_amdgcn_sinf(r);
#else
    return __sinf(r * 6.2831853071795864769f);
#endif
}

// ---------------- setup: amp GEMV (blocks 0..255) || prep (blocks 256..287) ----------------
__launch_bounds__(256)
__global__ void setup_kernel(const float* __restrict__ x,
                             const float* __restrict__ Wsw, const float* __restrict__ bsw,
                             const float* __restrict__ Wf0, const float* __restrict__ bf0,
                             const float* __restrict__ Wfv, const float* __restrict__ bfv,
                             const float* __restrict__ Wamp, const float* __restrict__ bamp,
                             const float* __restrict__ Wloc, const float* __restrict__ bloc,
                             const float* __restrict__ usw, const float* __restrict__ uloc,
                             float* __restrict__ ampT,
                             float* __restrict__ PmodR, float* __restrict__ vfreq,
                             unsigned short* __restrict__ tapsA, float* __restrict__ swb,
                             int* __restrict__ shiftb, unsigned int* __restrict__ maxb,
                             int* __restrict__ nmtb) {
    int tid = threadIdx.x;
    __shared__ float xs[128], f0t[128];
    __shared__ float redA[128]; __shared__ int redI[128];
    __shared__ float red0[128], red1[128], red2[128];
    __shared__ int maxHsh;

    if (blockIdx.x < 256) {
        // ---- amp part: amp = (x@W_amp+b)^2 -> ampT[b][fr][ch] ----
        int bq = blockIdx.x >> 6;          // 0..3 (8 b's each)
        int jt = blockIdx.x & 63;          // 256-wide j tile
        int j = jt * 256 + tid;
        float acc[8];
        float bj = bamp[j];
#pragma unroll
        for (int b = 0; b < 8; ++b) acc[b] = bj;
        const float* xb = x + bq * 8 * 128;
#pragma unroll 8
        for (int d = 0; d < 128; ++d) {
            float wv = Wamp[(size_t)d * 16384 + j];
#pragma unroll
            for (int b = 0; b < 8; ++b) acc[b] = fmaf(xb[b * 128 + d], wv, acc[b]);
        }
        int ch = j >> 7, fr = j & 127;
#pragma unroll
        for (int b = 0; b < 8; ++b) {
            float a = acc[b];
            ampT[(size_t)(bq * 8 + b) * 16384 + fr * 128 + ch] = a * a;
        }
        return;
    }

    // ---- prep part: one block per b ----
    int b = blockIdx.x - 256;
    if (tid < 64) maxb[b * 64 + tid] = 0u;
    if (tid == 0) maxHsh = 0;
    if (tid < 128) xs[tid] = x[b * 128 + tid];
    __syncthreads();

    // per-frame dots: threads 0..127 -> f0_var logits; 128..255 -> loc logits
    {
        int half = tid >> 7, fr = tid & 127;
        const float* W = half ? Wloc : Wfv;
        float a = (half ? bloc : bfv)[fr];
        for (int d = 0; d < 128; ++d) a = fmaf(xs[d], W[d * 128 + fr], a);
        if (half) { redA[fr] = sigmoidf_(a) + gumbelf_(uloc[b * 128 + fr]); redI[fr] = fr; }
        else      { f0t[fr] = sigmoidf_(a) * 2.0f - 1.0f; }   // f0var stash
    }
    if (tid < 128) {
        red0[tid] = xs[tid] * Wsw[tid * 2 + 0];
        red1[tid] = xs[tid] * Wsw[tid * 2 + 1];
        red2[tid] = xs[tid] * Wf0[tid];
    }
    __syncthreads();
    for (int off = 64; off > 0; off >>= 1) {
        if (tid < off) {
            red0[tid] += red0[tid + off];
            red1[tid] += red1[tid + off];
            red2[tid] += red2[tid + off];
            if (redA[tid + off] > redA[tid]) { redA[tid] = redA[tid + off]; redI[tid] = redI[tid + off]; }
        }
        __syncthreads();
    }
    float l0 = red0[0] + bsw[0], l1 = red1[0] + bsw[1];
    float g0 = gumbelf_(usw[b * 2 + 0]), g1 = gumbelf_(usw[b * 2 + 1]);
    float swv = (l0 + g0 >= l1 + g1) ? 1.0f : 0.0f;
    float sg = sigmoidf_(red2[0] + bf0[0]);
    float f0v = MIN_F_F + (sg * sg) * SPAN_F;
    if (tid == 0) { swb[b] = swv; shiftb[b] = redI[0] * 256; }
    if (tid < 128) {
        float f0var = f0t[tid];
        f0t[tid] = f0v + f0var * (f0v * 0.01f);
    }
    __syncthreads();

    // phase-prefix scan + taps, 4 waves x 16 h each; lane handles k=2l,2l+1
    int wave = tid >> 6, lane = tid & 63;
    int k0 = lane * 2, k1 = k0 + 1;
    int myMaxH = 0;
    for (int h = wave; h < 64; h += 4) {
        float hf = (float)(h + 1);
        size_t base = ((size_t)b * 64 + h) * 128;
        float vA = f0t[k0] * hf; vA = (vA > 1.0f) ? 0.0f : vA * PI_F;
        float vB = f0t[k1] * hf; vB = (vB > 1.0f) ? 0.0f : vB * PI_F;
        if (__any((vA > 0.0f) || (vB > 0.0f))) myMaxH = h;   // activity monotone in h
        double v0d = (double)vA, v1d = (double)vB;
        double sc = v0d + v1d;
#pragma unroll
        for (int d = 1; d < 64; d <<= 1) {
            double o = __shfl_up(sc, d);
            if (lane >= d) sc += o;
        }
        // P(k) = 128*(2*S(k) - v[k]); S(2l+1)=sc, S(2l)=sc-v1
        double P0 = 128.0 * (2.0 * sc - 2.0 * v1d - v0d);
        double P1 = 128.0 * (2.0 * sc - v1d);
        double r0 = P0 * INV_2PI; r0 -= floor(r0);
        double r1 = P1 * INV_2PI; r1 -= floor(r1);
        PmodR[base + k0] = (float)r0;
        PmodR[base + k1] = (float)r1;
        vfreq[base + k0] = vA * INV_2PI_F;
        vfreq[base + k1] = vB * INV_2PI_F;
        // taps (depend only on v0 of this h)
        float v0_rad = __shfl(vA, 0);
        double v0rev = (double)v0_rad * INV_2PI;
#pragma unroll
        for (int kk = 0; kk < 2; ++kk) {
            int k = k0 + kk;
            float hwk = 0.54f - 0.46f * cosf(6.2831853071795864769f * (float)k / 128.0f);
            double rv = (double)(k + 1) * v0rev; rv -= floor(rv);
            float sv = __sinf((float)(rv * TWO_PI));
            float tv = sv * hwk * INV_SQRT_N;
            int c = k >> 3, e = 7 - (k & 7);
            tapsA[base + 8 * (c ^ (h & 7)) + e] = f2bf(tv);
        }
    }
    if (lane == 0) atomicMax(&maxHsh, myMaxH);
    __syncthreads();
    if (tid == 0) nmtb[b] = (maxHsh >> 4) + 1;
}

// Conv core notes:
//   k-fill convention (same for A and B, so any HW k-permutation cancels):
//     frag[r] corresponds to logical k = 32*ks + 8*(lane>>4) + (7 - r)
//   A (taps) stored pre-reversed -> one aligned b128 per (mt,ks)
//   B: wsh[s][t] = w[t+s], chunk c stored at c^s -> one aligned, conflict-free b128
//   Dead-harmonic skip: COMPILE-TIME via template<NMT> + uniform switch (R8 lesson:
//   runtime per-mt guards around MFMA destroy pipelining). R10-R12 lessons: wave-per-mt
//   remap, ampconv fusion, and lo/hi kernel split each regressed ~4.5us vs this config.

// ---------------- pass 1 core ----------------
template<int NMT>
__device__ __forceinline__ void convmax_core(int tid, const short* tapsL,
                                             const short (*wsh)[640],
                                             unsigned int* maxL) {
    int lane = tid & 63, w = tid >> 6;
    int g = lane >> 4, col = lane & 15, s_l = lane & 7, b3 = (lane >> 3) & 1;
    short8v fa[NMT][4];
#pragma unroll
    for (int mt = 0; mt < NMT; ++mt)
#pragma unroll
        for (int ks = 0; ks < 4; ++ks) {
            int row = 16 * mt + col;
            int ch = (4 * ks + g) ^ (row & 7);
            fa[mt][ks] = *(const short8v*)&tapsL[row * 128 + 8 * ch];
        }
    float rm[NMT * 4];
#pragma unroll
    for (int i = 0; i < NMT * 4; ++i) rm[i] = 0.0f;
    for (int ntl = 0; ntl < 8; ++ntl) {
        int nt = w * 8 + ntl;
        short8v fb[4];
#pragma unroll
        for (int ks = 0; ks < 4; ++ks) {
            int t0 = 120 + 16 * nt - 32 * ks - 8 * g + 8 * b3;
            int ch = (t0 >> 3) ^ s_l;
            fb[ks] = *(const short8v*)&wsh[s_l][8 * ch];
        }
        f32x4 acc[NMT];
#pragma unroll
        for (int mt = 0; mt < NMT; ++mt) acc[mt] = (f32x4){0, 0, 0, 0};
#pragma unroll
        for (int ks = 0; ks < 4; ++ks)
#pragma unroll
            for (int mt = 0; mt < NMT; ++mt)
                acc[mt] = __builtin_amdgcn_mfma_f32_16x16x32_bf16(fa[mt][ks], fb[ks], acc[mt], 0, 0, 0);
#pragma unroll
        for (int mt = 0; mt < NMT; ++mt)
#pragma unroll
            for (int q = 0; q < 4; ++q) rm[mt * 4 + q] = fmaxf(rm[mt * 4 + q], fabsf(acc[mt][q]));
    }
#pragma unroll
    for (int i = 0; i < NMT * 4; ++i) {
        float m = rm[i];
        m = fmaxf(m, __shfl_xor(m, 1));
        m = fmaxf(m, __shfl_xor(m, 2));
        m = fmaxf(m, __shfl_xor(m, 4));
        m = fmaxf(m, __shfl_xor(m, 8));
        if (col == 0) atomicMax(&maxL[16 * (i >> 2) + 4 * g + (i & 3)], __float_as_uint(m));
    }
}

// ---------------- pass 1: MFMA circular FIR, 1 tile/block, per-(b,h) row max ----
__launch_bounds__(256)
__global__ void convmax_kernel(const float* __restrict__ noise,
                               const unsigned short* __restrict__ tapsA,
                               const float* __restrict__ swb,
                               const int* __restrict__ nmtb,
                               unsigned int* __restrict__ maxb) {
    int b = blockIdx.y;
    if (swb[b] == 0.0f) return;
    int nmt = nmtb[b];
    int tid = threadIdx.x;
    int T = blockIdx.x * 512;
    __shared__ short tapsL[64 * 128];
    __shared__ short wsh[8][640];
    __shared__ float wf[640];
    __shared__ unsigned maxL[64];
    if (tid < 64) maxL[tid] = 0u;
    {
        const short8v* src = (const short8v*)(tapsA + ((size_t)b << 13));
        short8v* dst = (short8v*)tapsL;
        for (int i = tid; i < 1024; i += 256) dst[i] = src[i];
    }
    for (int i = tid; i < 640; i += 256)
        wf[i] = noise[(size_t)b * NSAMP + ((T - 127 + i) & NMASK)] * 2.0f - 1.0f;
    __syncthreads();
    for (int idx = tid; idx < 640; idx += 256) {
        int c = idx >> 3, s = idx & 7;
        short8v v;
#pragma unroll
        for (int e = 0; e < 8; ++e) {
            int t = 8 * c + e + s; t = t < 640 ? t : 639;
            v[e] = (short)f2bf(wf[t]);
        }
        *(short8v*)&wsh[s][8 * (c ^ s)] = v;
    }
    __syncthreads();
    switch (nmt) {
        case 1: convmax_core<1>(tid, tapsL, wsh, maxL); break;
        case 2: convmax_core<2>(tid, tapsL, wsh, maxL); break;
        case 3: convmax_core<3>(tid, tapsL, wsh, maxL); break;
        default: convmax_core<4>(tid, tapsL, wsh, maxL); break;
    }
    __syncthreads();
    if (tid < 64 && tid < nmt * 16) atomicMax(&maxb[b * 64 + tid], maxL[tid]);
}

// ---------------- pass 2 core ----------------
template<int NMT>
__device__ __forceinline__ void final_core(int b, int T, int tid, int s0, int shift,
                                           const short* tapsL, const short (*wsh)[640],
                                           const float4 (*seg)[64],
                                           const float (*ampA)[64], const float (*ampBn)[64],
                                           float (*part)[520], float* __restrict__ out) {
    int lane = tid & 63, w = tid >> 6;
    int g = lane >> 4, col = lane & 15, s_l = lane & 7, b3 = (lane >> 3) & 1;
    short8v fa[NMT][4];
#pragma unroll
    for (int mt = 0; mt < NMT; ++mt)
#pragma unroll
        for (int ks = 0; ks < 4; ++ks) {
            int row = 16 * mt + col;
            int ch = (4 * ks + g) ^ (row & 7);
            fa[mt][ks] = *(const short8v*)&tapsL[row * 128 + 8 * ch];
        }
    int dd = (w + 1) >> 1;                 // per-thread constant segment slot {0,1,1,2}
    bool head = (T + w * 128) < 128;       // only block 0, w==0
    float vsr[NMT * 4], dvr[NMT * 4], pbr[NMT * 4];
#pragma unroll
    for (int mt = 0; mt < NMT; ++mt)
#pragma unroll
        for (int q = 0; q < 4; ++q) {
            int i = mt * 4 + q, h = 16 * mt + 4 * g + q;
            float4 sgv = seg[dd][h];
            vsr[i] = sgv.x;
            dvr[i] = head ? 0.0f : sgv.y;
            pbr[i] = head ? (-128.0f * sgv.x) : sgv.z;   // head: p=(t+1)*v0 with m=t+129
        }
    // per-thread frame slot is ntl-invariant (128-sample span, T%512==0)
    int t_0 = T + w * 128 + col;
    int lo0 = (t_0 < 128) ? 0 : ((t_0 - 128) >> 8);
    int dlo = lo0 - s0;              // dhi = dlo+1 <= 3
    float loF = (float)lo0;
    f32x4 aloA[NMT], adA[NMT], aloB[NMT], adB[NMT];
#pragma unroll
    for (int mt = 0; mt < NMT; ++mt) {
        int h4 = 16 * mt + 4 * g;
        aloA[mt] = *(const f32x4*)&ampA[dlo][h4];
        adA[mt]  = *(const f32x4*)&ampA[dlo + 1][h4] - aloA[mt];
        aloB[mt] = *(const f32x4*)&ampBn[dlo][h4];
        adB[mt]  = *(const f32x4*)&ampBn[dlo + 1][h4] - aloB[mt];
    }
    __syncthreads();

    for (int ntl = 0; ntl < 8; ++ntl) {
        int nt = w * 8 + ntl;
        short8v fb[4];
#pragma unroll
        for (int ks = 0; ks < 4; ++ks) {
            int t0 = 120 + 16 * nt - 32 * ks - 8 * g + 8 * b3;
            int ch = (t0 >> 3) ^ s_l;
            fb[ks] = *(const short8v*)&wsh[s_l][8 * ch];
        }
        f32x4 acc[NMT];
#pragma unroll
        for (int mt = 0; mt < NMT; ++mt) acc[mt] = (f32x4){0, 0, 0, 0};
#pragma unroll
        for (int ks = 0; ks < 4; ++ks)
#pragma unroll
            for (int mt = 0; mt < NMT; ++mt)
                acc[mt] = __builtin_amdgcn_mfma_f32_16x16x32_bf16(fa[mt][ks], fb[ks], acc[mt], 0, 0, 0);

        int j = w * 128 + ntl * 16 + col;
        int t = T + j;
        float coords = ((float)t + 0.5f) * (1.0f / 256.0f) - 0.5f;
        coords = fminf(fmaxf(coords, 0.0f), 127.0f);
        float w1 = coords - loF;
        float mp1 = (float)(((t - 128) & 255) + 1);
        float mp2 = mp1 * mp1;
        float psum = 0.0f;
#pragma unroll
        for (int mt = 0; mt < NMT; ++mt) {
#pragma unroll
            for (int q = 0; q < 4; ++q) {
                int i = mt * 4 + q;
                float p = fmaf(mp2, dvr[i], fmaf(mp1, vsr[i], pbr[i]));
                p -= floorf(p);
                float sv = sinrev(p);
                float aA = fmaf(w1, adA[mt][q], aloA[mt][q]);
                float aB = fmaf(w1, adB[mt][q], aloB[mt][q]);
                psum = fmaf(sv, aA, psum);
                psum = fmaf(acc[mt][q], aB, psum);
            }
        }
        part[g][j] = psum;
    }
    __syncthreads();
#pragma unroll
    for (int rep = 0; rep < 2; ++rep) {
        int j2 = rep * 256 + tid;
        float r = part[0][j2] + part[1][j2] + part[2][j2] + part[3][j2];
        int pos = (T + j2 + shift) & NMASK;
        out[(size_t)b * NSAMP + pos] = r;
    }
}

// ---------------- pass 2: fused MFMA conv + revolutions sine + reg-hoisted amp lerp ----
__launch_bounds__(256)
__global__ void final_kernel(const float* __restrict__ noise,
                             const unsigned short* __restrict__ tapsA,
                             const float* __restrict__ PmodR, const float* __restrict__ vfreq,
                             const float* __restrict__ ampT,
                             const unsigned int* __restrict__ maxb,
                             const float* __restrict__ swb, const int* __restrict__ shiftb,
                             const int* __restrict__ nmtb,
                             float* __restrict__ out) {
    int b = blockIdx.y;
    int T = blockIdx.x * 512, tid = threadIdx.x;
    if (swb[b] == 0.0f) {
        out[(size_t)b * NSAMP + T + tid] = 0.0f;
        out[(size_t)b * NSAMP + T + 256 + tid] = 0.0f;
        return;
    }
    int nmt = nmtb[b];
    __shared__ union { short tapsL[64 * 128]; float part[4][520]; } R;
    __shared__ short wsh[8][640];
    __shared__ float wf[640];
    __shared__ float4 seg[3][64];     // (vs_rev, dv_rev, Pb_rev, -) per (segment-slot, h)
    __shared__ float ampA[4][64], ampBn[4][64];  // SoA, invn folded into B

    int s0 = (T >> 8) - 1;
    // ---- phase A: global loads ----
    for (int i = tid; i < 640; i += 256)
        wf[i] = noise[(size_t)b * NSAMP + ((T - 127 + i) & NMASK)] * 2.0f - 1.0f;
    {
        const short8v* src = (const short8v*)(tapsA + ((size_t)b << 13));
        short8v* dst = (short8v*)R.tapsL;
        for (int i = tid; i < 1024; i += 256) dst[i] = src[i];
    }
    {
        int ad = tid >> 6, ah = tid & 63;
        int afr = min(max(s0 + ad, 0), 127);
        float aAv = ampT[(size_t)b * 16384 + afr * 128 + ah];
        float aBv = ampT[(size_t)b * 16384 + afr * 128 + 64 + ah];
        float invn = 1.0f / (__uint_as_float(maxb[b * 64 + ah]) + 1e-8f);
        ampA[ad][ah] = aAv;
        ampBn[ad][ah] = aBv * invn;
    }
    if (tid < 192) {
        int dd = tid >> 6, h2 = tid & 63;
        size_t vb = ((size_t)(b * 64 + h2)) * 128;
        int s = min(max(s0 + dd, 0), 127), s1 = min(s + 1, 127);
        float vs = vfreq[vb + s], vs1 = vfreq[vb + s1];
        float4 sgv;
        sgv.x = vs;
        sgv.y = (vs1 - vs) * (1.0f / 512.0f);
        sgv.z = PmodR[vb + s];
        sgv.w = 0.0f;
        seg[dd][h2] = sgv;
    }
    __syncthreads();
    // ---- phase B: wsh build, then templated core (fa/seg/amp hoists + main loop) ----
    for (int idx = tid; idx < 640; idx += 256) {
        int c = idx >> 3, s = idx & 7;
        short8v v;
#pragma unroll
        for (int e = 0; e < 8; ++e) {
            int t = 8 * c + e + s; t = t < 640 ? t : 639;
            v[e] = (short)f2bf(wf[t]);
        }
        *(short8v*)&wsh[s][8 * (c ^ s)] = v;
    }
    int shift = shiftb[b];
    switch (nmt) {
        case 1: final_core<1>(b, T, tid, s0, shift, R.tapsL, wsh, seg, ampA, ampBn, R.part, out); break;
        case 2: final_core<2>(b, T, tid, s0, shift, R.tapsL, wsh, seg, ampA, ampBn, R.part, out); break;
        case 3: final_core<3>(b, T, tid, s0, shift, R.tapsL, wsh, seg, ampA, ampBn, R.part, out); break;
        default: final_core<4>(b, T, tid, s0, shift, R.tapsL, wsh, seg, ampA, ampBn, R.part, out); break;
    }
}

extern "C" void kernel_launch(void* const* d_in, const int* in_sizes, int n_in,
                              void* d_out, int out_size, void* d_ws, size_t ws_size,
                              hipStream_t stream) {
    const float* x     = (const float*)d_in[0];
    const float* Wsw   = (const float*)d_in[1];
    const float* bsw   = (const float*)d_in[2];
    const float* Wf0   = (const float*)d_in[3];
    const float* bf0   = (const float*)d_in[4];
    const float* Wfv   = (const float*)d_in[5];
    const float* bfv   = (const float*)d_in[6];
    const float* Wamp  = (const float*)d_in[7];
    const float* bamp  = (const float*)d_in[8];
    const float* Wloc  = (const float*)d_in[9];
    const float* bloc  = (const float*)d_in[10];
    const float* usw   = (const float*)d_in[11];
    const float* uloc  = (const float*)d_in[12];
    const float* noise = (const float*)d_in[13];

    char* ws = (char*)d_ws;
    float*    PmodR  = (float*)(ws + OFF_PM);
    float*    vfreq  = (float*)(ws + OFF_V);
    unsigned short* tapsA = (unsigned short*)(ws + OFF_TA);
    float*    ampT   = (float*)(ws + OFF_A);
    unsigned* maxb   = (unsigned*)(ws + OFF_M);
    float*    swb    = (float*)(ws + OFF_SW);
    int*      shiftb = (int*)(ws + OFF_SH);
    int*      nmtb   = (int*)(ws + OFF_NM);
    float*    out    = (float*)d_out;

    setup_kernel<<<dim3(288), 256, 0, stream>>>(x, Wsw, bsw, Wf0, bf0, Wfv, bfv, Wamp, bamp,
                                                Wloc, bloc, usw, uloc, ampT,
                                                PmodR, vfreq, tapsA, swb, shiftb, maxb, nmtb);
    convmax_kernel<<<dim3(64, 32), 256, 0, stream>>>(noise, tapsA, swb, nmtb, maxb);
    final_kernel<<<dim3(64, 32), 256, 0, stream>>>(noise, tapsA, PmodR, vfreq, ampT, maxb,
                                                   swb, shiftb, nmtb, out);
}

// Round 14
// 49.297 us; speedup vs baseline: 1.1035x; 1.0167x over previous
//
#include <hip/hip_runtime.h>
#include <math.h>

typedef __attribute__((ext_vector_type(8))) short short8v;   // 8 bf16 (4 VGPRs)
typedef __attribute__((ext_vector_type(4))) float f32x4;

namespace {
constexpr int NSAMP = 32768;
constexpr int NMASK = NSAMP - 1;
constexpr float MIN_F_F = (float)(30.0 / 11025.0);
constexpr float SPAN_F  = (float)(3000.0 / 11025.0 - 30.0 / 11025.0);
constexpr float PI_F    = 3.14159265358979323846f;
constexpr double TWO_PI  = 6.283185307179586476925287;
constexpr double INV_2PI = 0.159154943091895335768884;
constexpr float INV_2PI_F = 0.15915494309189533577f;
constexpr float INV_SQRT_N = 0.00552427172801990295f; // 1/sqrt(32768)

// ws layout (bytes)
constexpr size_t OFF_PM = 0;                          // float PmodR [32][64][128]  1 MB
constexpr size_t OFF_V  = OFF_PM + 32*64*128*4;       // float vfreq [32][64][128]  1 MB
constexpr size_t OFF_TA = OFF_V  + 32*64*128*4;       // u16   tapsA [32][64][128]  512 KB
constexpr size_t OFF_A  = OFF_TA + 32*64*128*2;       // float ampT  [32][128fr][128ch] 2 MB
constexpr size_t OFF_M  = OFF_A  + 32*128*128*4;      // uint  maxb  [2048]
constexpr size_t OFF_SW = OFF_M  + 2048*4;            // float swb   [32]
constexpr size_t OFF_SH = OFF_SW + 32*4;              // int   shiftb[32]
constexpr size_t OFF_NM = OFF_SH + 32*4;              // int   nmtb  [32] (active 16-h blocks)
}

__device__ __forceinline__ float sigmoidf_(float z) { return 1.0f / (1.0f + expf(-z)); }
__device__ __forceinline__ float gumbelf_(float u) { return -logf(-logf(u + 1e-10f) + 1e-10f); }
__device__ __forceinline__ unsigned short f2bf(float f) {
    unsigned u = __float_as_uint(f);
    return (unsigned short)((u + 0x7FFFu + ((u >> 16) & 1u)) >> 16);
}
__device__ __forceinline__ float fract_(float p) {   // p - floor(p), single v_fract
#if __has_builtin(__builtin_amdgcn_fractf)
    return __builtin_amdgcn_fractf(p);
#else
    return p - floorf(p);
#endif
}
__device__ __forceinline__ float sinrev(float r) {   // r in [0,1): sin(2*pi*r)
#if __has_builtin(__builtin_amdgcn_sinf)
    return __builtin_amdgcn_sinf(r);
#else
    return __sinf(r * 6.2831853071795864769f);
#endif
}

// ---------------- setup: amp GEMV (blocks 0..255) || prep (blocks 256..287) ----------------
__launch_bounds__(256)
__global__ void setup_kernel(const float* __restrict__ x,
                             const float* __restrict__ Wsw, const float* __restrict__ bsw,
                             const float* __restrict__ Wf0, const float* __restrict__ bf0,
                             const float* __restrict__ Wfv, const float* __restrict__ bfv,
                             const float* __restrict__ Wamp, const float* __restrict__ bamp,
                             const float* __restrict__ Wloc, const float* __restrict__ bloc,
                             const float* __restrict__ usw, const float* __restrict__ uloc,
                             float* __restrict__ ampT,
                             float* __restrict__ PmodR, float* __restrict__ vfreq,
                             unsigned short* __restrict__ tapsA, float* __restrict__ swb,
                             int* __restrict__ shiftb, unsigned int* __restrict__ maxb,
                             int* __restrict__ nmtb) {
    int tid = threadIdx.x;
    __shared__ float xs[128], f0t[128];
    __shared__ float redA[128]; __shared__ int redI[128];
    __shared__ float red0[128], red1[128], red2[128];
    __shared__ int maxHsh;

    if (blockIdx.x < 256) {
        // ---- amp part: amp = (x@W_amp+b)^2 -> ampT[b][fr][ch] ----
        int bq = blockIdx.x >> 6;          // 0..3 (8 b's each)
        int jt = blockIdx.x & 63;          // 256-wide j tile
        int j = jt * 256 + tid;
        float acc[8];
        float bj = bamp[j];
#pragma unroll
        for (int b = 0; b < 8; ++b) acc[b] = bj;
        const float* xb = x + bq * 8 * 128;
#pragma unroll 8
        for (int d = 0; d < 128; ++d) {
            float wv = Wamp[(size_t)d * 16384 + j];
#pragma unroll
            for (int b = 0; b < 8; ++b) acc[b] = fmaf(xb[b * 128 + d], wv, acc[b]);
        }
        int ch = j >> 7, fr = j & 127;
#pragma unroll
        for (int b = 0; b < 8; ++b) {
            float a = acc[b];
            ampT[(size_t)(bq * 8 + b) * 16384 + fr * 128 + ch] = a * a;
        }
        return;
    }

    // ---- prep part: one block per b ----
    int b = blockIdx.x - 256;
    if (tid < 64) maxb[b * 64 + tid] = 0u;
    if (tid == 0) maxHsh = 0;
    if (tid < 128) xs[tid] = x[b * 128 + tid];
    __syncthreads();

    // per-frame dots: threads 0..127 -> f0_var logits; 128..255 -> loc logits
    {
        int half = tid >> 7, fr = tid & 127;
        const float* W = half ? Wloc : Wfv;
        float a = (half ? bloc : bfv)[fr];
        for (int d = 0; d < 128; ++d) a = fmaf(xs[d], W[d * 128 + fr], a);
        if (half) { redA[fr] = sigmoidf_(a) + gumbelf_(uloc[b * 128 + fr]); redI[fr] = fr; }
        else      { f0t[fr] = sigmoidf_(a) * 2.0f - 1.0f; }   // f0var stash
    }
    if (tid < 128) {
        red0[tid] = xs[tid] * Wsw[tid * 2 + 0];
        red1[tid] = xs[tid] * Wsw[tid * 2 + 1];
        red2[tid] = xs[tid] * Wf0[tid];
    }
    __syncthreads();
    for (int off = 64; off > 0; off >>= 1) {
        if (tid < off) {
            red0[tid] += red0[tid + off];
            red1[tid] += red1[tid + off];
            red2[tid] += red2[tid + off];
            if (redA[tid + off] > redA[tid]) { redA[tid] = redA[tid + off]; redI[tid] = redI[tid + off]; }
        }
        __syncthreads();
    }
    float l0 = red0[0] + bsw[0], l1 = red1[0] + bsw[1];
    float g0 = gumbelf_(usw[b * 2 + 0]), g1 = gumbelf_(usw[b * 2 + 1]);
    float swv = (l0 + g0 >= l1 + g1) ? 1.0f : 0.0f;
    float sg = sigmoidf_(red2[0] + bf0[0]);
    float f0v = MIN_F_F + (sg * sg) * SPAN_F;
    if (tid == 0) { swb[b] = swv; shiftb[b] = redI[0] * 256; }
    if (tid < 128) {
        float f0var = f0t[tid];
        f0t[tid] = f0v + f0var * (f0v * 0.01f);
    }
    __syncthreads();

    // phase-prefix scan + taps, 4 waves x 16 h each; lane handles k=2l,2l+1
    int wave = tid >> 6, lane = tid & 63;
    int k0 = lane * 2, k1 = k0 + 1;
    int myMaxH = 0;
    for (int h = wave; h < 64; h += 4) {
        float hf = (float)(h + 1);
        size_t base = ((size_t)b * 64 + h) * 128;
        float vA = f0t[k0] * hf; vA = (vA > 1.0f) ? 0.0f : vA * PI_F;
        float vB = f0t[k1] * hf; vB = (vB > 1.0f) ? 0.0f : vB * PI_F;
        if (__any((vA > 0.0f) || (vB > 0.0f))) myMaxH = h;   // activity monotone in h
        double v0d = (double)vA, v1d = (double)vB;
        double sc = v0d + v1d;
#pragma unroll
        for (int d = 1; d < 64; d <<= 1) {
            double o = __shfl_up(sc, d);
            if (lane >= d) sc += o;
        }
        // P(k) = 128*(2*S(k) - v[k]); S(2l+1)=sc, S(2l)=sc-v1
        double P0 = 128.0 * (2.0 * sc - 2.0 * v1d - v0d);
        double P1 = 128.0 * (2.0 * sc - v1d);
        double r0 = P0 * INV_2PI; r0 -= floor(r0);
        double r1 = P1 * INV_2PI; r1 -= floor(r1);
        PmodR[base + k0] = (float)r0;
        PmodR[base + k1] = (float)r1;
        vfreq[base + k0] = vA * INV_2PI_F;
        vfreq[base + k1] = vB * INV_2PI_F;
        // taps (depend only on v0 of this h)
        float v0_rad = __shfl(vA, 0);
        double v0rev = (double)v0_rad * INV_2PI;
#pragma unroll
        for (int kk = 0; kk < 2; ++kk) {
            int k = k0 + kk;
            float hwk = 0.54f - 0.46f * cosf(6.2831853071795864769f * (float)k / 128.0f);
            double rv = (double)(k + 1) * v0rev; rv -= floor(rv);
            float sv = __sinf((float)(rv * TWO_PI));
            float tv = sv * hwk * INV_SQRT_N;
            int c = k >> 3, e = 7 - (k & 7);
            tapsA[base + 8 * (c ^ (h & 7)) + e] = f2bf(tv);
        }
    }
    if (lane == 0) atomicMax(&maxHsh, myMaxH);
    __syncthreads();
    if (tid == 0) nmtb[b] = (maxHsh >> 4) + 1;
}

// Conv core notes:
//   k-fill convention (same for A and B, so any HW k-permutation cancels):
//     frag[r] corresponds to logical k = 32*ks + 8*(lane>>4) + (7 - r)
//   A (taps) stored pre-reversed -> one aligned b128 per (mt,ks)
//   B: wsh[s][t] = w[t+s], chunk c stored at c^s -> one aligned, conflict-free b128
//   Dead-harmonic skip: COMPILE-TIME via template<NMT> + uniform switch (R8 lesson:
//   runtime per-mt guards around MFMA destroy pipelining). R10-R12 lessons: wave-per-mt
//   remap, ampconv fusion, and lo/hi kernel split each regressed ~4.5us vs this config.

// ---------------- pass 1 core ----------------
template<int NMT>
__device__ __forceinline__ void convmax_core(int tid, const short* tapsL,
                                             const short (*wsh)[640],
                                             unsigned int* maxL) {
    int lane = tid & 63, w = tid >> 6;
    int g = lane >> 4, col = lane & 15, s_l = lane & 7, b3 = (lane >> 3) & 1;
    short8v fa[NMT][4];
#pragma unroll
    for (int mt = 0; mt < NMT; ++mt)
#pragma unroll
        for (int ks = 0; ks < 4; ++ks) {
            int row = 16 * mt + col;
            int ch = (4 * ks + g) ^ (row & 7);
            fa[mt][ks] = *(const short8v*)&tapsL[row * 128 + 8 * ch];
        }
    float rm[NMT * 4];
#pragma unroll
    for (int i = 0; i < NMT * 4; ++i) rm[i] = 0.0f;
    for (int ntl = 0; ntl < 8; ++ntl) {
        int nt = w * 8 + ntl;
        short8v fb[4];
#pragma unroll
        for (int ks = 0; ks < 4; ++ks) {
            int t0 = 120 + 16 * nt - 32 * ks - 8 * g + 8 * b3;
            int ch = (t0 >> 3) ^ s_l;
            fb[ks] = *(const short8v*)&wsh[s_l][8 * ch];
        }
        f32x4 acc[NMT];
#pragma unroll
        for (int mt = 0; mt < NMT; ++mt) acc[mt] = (f32x4){0, 0, 0, 0};
#pragma unroll
        for (int ks = 0; ks < 4; ++ks)
#pragma unroll
            for (int mt = 0; mt < NMT; ++mt)
                acc[mt] = __builtin_amdgcn_mfma_f32_16x16x32_bf16(fa[mt][ks], fb[ks], acc[mt], 0, 0, 0);
#pragma unroll
        for (int mt = 0; mt < NMT; ++mt)
#pragma unroll
            for (int q = 0; q < 4; ++q) rm[mt * 4 + q] = fmaxf(rm[mt * 4 + q], fabsf(acc[mt][q]));
    }
#pragma unroll
    for (int i = 0; i < NMT * 4; ++i) {
        float m = rm[i];
        m = fmaxf(m, __shfl_xor(m, 1));
        m = fmaxf(m, __shfl_xor(m, 2));
        m = fmaxf(m, __shfl_xor(m, 4));
        m = fmaxf(m, __shfl_xor(m, 8));
        if (col == 0) atomicMax(&maxL[16 * (i >> 2) + 4 * g + (i & 3)], __float_as_uint(m));
    }
}

// ---------------- pass 1: MFMA circular FIR, 1 tile/block, per-(b,h) row max ----
__launch_bounds__(256)
__global__ void convmax_kernel(const float* __restrict__ noise,
                               const unsigned short* __restrict__ tapsA,
                               const float* __restrict__ swb,
                               const int* __restrict__ nmtb,
                               unsigned int* __restrict__ maxb) {
    int b = blockIdx.y;
    if (swb[b] == 0.0f) return;
    int nmt = nmtb[b];
    int tid = threadIdx.x;
    int T = blockIdx.x * 512;
    __shared__ short tapsL[64 * 128];
    __shared__ short wsh[8][640];
    __shared__ float wf[640];
    __shared__ unsigned maxL[64];
    if (tid < 64) maxL[tid] = 0u;
    {
        const short8v* src = (const short8v*)(tapsA + ((size_t)b << 13));
        short8v* dst = (short8v*)tapsL;
        for (int i = tid; i < 1024; i += 256) dst[i] = src[i];
    }
    for (int i = tid; i < 640; i += 256)
        wf[i] = noise[(size_t)b * NSAMP + ((T - 127 + i) & NMASK)] * 2.0f - 1.0f;
    __syncthreads();
    for (int idx = tid; idx < 640; idx += 256) {
        int c = idx >> 3, s = idx & 7;
        short8v v;
#pragma unroll
        for (int e = 0; e < 8; ++e) {
            int t = 8 * c + e + s; t = t < 640 ? t : 639;
            v[e] = (short)f2bf(wf[t]);
        }
        *(short8v*)&wsh[s][8 * (c ^ s)] = v;
    }
    __syncthreads();
    switch (nmt) {
        case 1: convmax_core<1>(tid, tapsL, wsh, maxL); break;
        case 2: convmax_core<2>(tid, tapsL, wsh, maxL); break;
        case 3: convmax_core<3>(tid, tapsL, wsh, maxL); break;
        default: convmax_core<4>(tid, tapsL, wsh, maxL); break;
    }
    __syncthreads();
    if (tid < 64 && tid < nmt * 16) atomicMax(&maxb[b * 64 + tid], maxL[tid]);
}

// ---------------- pass 2 core ----------------
template<int NMT>
__device__ __forceinline__ void final_core(int b, int T, int tid, int s0, int shift,
                                           const short* tapsL, const short (*wsh)[640],
                                           const float4 (*seg)[64],
                                           const float (*ampA)[64], const float (*ampBn)[64],
                                           float (*part)[520], float* __restrict__ out) {
    int lane = tid & 63, w = tid >> 6;
    int g = lane >> 4, col = lane & 15, s_l = lane & 7, b3 = (lane >> 3) & 1;
    short8v fa[NMT][4];
#pragma unroll
    for (int mt = 0; mt < NMT; ++mt)
#pragma unroll
        for (int ks = 0; ks < 4; ++ks) {
            int row = 16 * mt + col;
            int ch = (4 * ks + g) ^ (row & 7);
            fa[mt][ks] = *(const short8v*)&tapsL[row * 128 + 8 * ch];
        }
    int dd = (w + 1) >> 1;                 // per-thread constant segment slot {0,1,1,2}
    bool head = (T + w * 128) < 128;       // only block 0, w==0
    float vsr[NMT * 4], dvr[NMT * 4], pbr[NMT * 4];
#pragma unroll
    for (int mt = 0; mt < NMT; ++mt)
#pragma unroll
        for (int q = 0; q < 4; ++q) {
            int i = mt * 4 + q, h = 16 * mt + 4 * g + q;
            float4 sgv = seg[dd][h];
            vsr[i] = sgv.x;
            dvr[i] = head ? 0.0f : sgv.y;
            pbr[i] = head ? (-128.0f * sgv.x) : sgv.z;   // head: p=(t+1)*v0 with m=t+129
        }
    // per-thread frame slot is ntl-invariant (128-sample span, T%512==0)
    int t_0 = T + w * 128 + col;
    int lo0 = (t_0 < 128) ? 0 : ((t_0 - 128) >> 8);
    int dlo = lo0 - s0;              // dhi = dlo+1 <= 3
    float loF = (float)lo0;
    f32x4 aloA[NMT], adA[NMT], aloB[NMT], adB[NMT];
#pragma unroll
    for (int mt = 0; mt < NMT; ++mt) {
        int h4 = 16 * mt + 4 * g;
        aloA[mt] = *(const f32x4*)&ampA[dlo][h4];
        adA[mt]  = *(const f32x4*)&ampA[dlo + 1][h4] - aloA[mt];
        aloB[mt] = *(const f32x4*)&ampBn[dlo][h4];
        adB[mt]  = *(const f32x4*)&ampBn[dlo + 1][h4] - aloB[mt];
    }
    __syncthreads();

    for (int ntl = 0; ntl < 8; ++ntl) {
        int nt = w * 8 + ntl;
        short8v fb[4];
#pragma unroll
        for (int ks = 0; ks < 4; ++ks) {
            int t0 = 120 + 16 * nt - 32 * ks - 8 * g + 8 * b3;
            int ch = (t0 >> 3) ^ s_l;
            fb[ks] = *(const short8v*)&wsh[s_l][8 * ch];
        }
        f32x4 acc[NMT];
#pragma unroll
        for (int mt = 0; mt < NMT; ++mt) acc[mt] = (f32x4){0, 0, 0, 0};
#pragma unroll
        for (int ks = 0; ks < 4; ++ks)
#pragma unroll
            for (int mt = 0; mt < NMT; ++mt)
                acc[mt] = __builtin_amdgcn_mfma_f32_16x16x32_bf16(fa[mt][ks], fb[ks], acc[mt], 0, 0, 0);

        int j = w * 128 + ntl * 16 + col;
        int t = T + j;
        float coords = ((float)t + 0.5f) * (1.0f / 256.0f) - 0.5f;
        coords = fminf(fmaxf(coords, 0.0f), 127.0f);
        float w1 = coords - loF;
        float mp1 = (float)(((t - 128) & 255) + 1);
        float mp2 = mp1 * mp1;
        float psum = 0.0f;
#pragma unroll
        for (int mt = 0; mt < NMT; ++mt) {
#pragma unroll
            for (int q = 0; q < 4; ++q) {
                int i = mt * 4 + q;
                float p = fmaf(mp2, dvr[i], fmaf(mp1, vsr[i], pbr[i]));
                float sv = sinrev(fract_(p));
                float aA = fmaf(w1, adA[mt][q], aloA[mt][q]);
                float aB = fmaf(w1, adB[mt][q], aloB[mt][q]);
                psum = fmaf(sv, aA, psum);
                psum = fmaf(acc[mt][q], aB, psum);
            }
        }
        part[g][j] = psum;
    }
    __syncthreads();
#pragma unroll
    for (int rep = 0; rep < 2; ++rep) {
        int j2 = rep * 256 + tid;
        float r = part[0][j2] + part[1][j2] + part[2][j2] + part[3][j2];
        int pos = (T + j2 + shift) & NMASK;
        out[(size_t)b * NSAMP + pos] = r;
    }
}

// ---------------- pass 2: fused MFMA conv + revolutions sine + reg-hoisted amp lerp ----
__launch_bounds__(256)
__global__ void final_kernel(const float* __restrict__ noise,
                             const unsigned short* __restrict__ tapsA,
                             const float* __restrict__ PmodR, const float* __restrict__ vfreq,
                             const float* __restrict__ ampT,
                             const unsigned int* __restrict__ maxb,
                             const float* __restrict__ swb, const int* __restrict__ shiftb,
                             const int* __restrict__ nmtb,
                             float* __restrict__ out) {
    int b = blockIdx.y;
    int T = blockIdx.x * 512, tid = threadIdx.x;
    if (swb[b] == 0.0f) {
        out[(size_t)b * NSAMP + T + tid] = 0.0f;
        out[(size_t)b * NSAMP + T + 256 + tid] = 0.0f;
        return;
    }
    int nmt = nmtb[b];
    __shared__ union { short tapsL[64 * 128]; float part[4][520]; } R;
    __shared__ short wsh[8][640];
    __shared__ float wf[640];
    __shared__ float4 seg[3][64];     // (vs_rev, dv_rev, Pb_rev, -) per (segment-slot, h)
    __shared__ float ampA[4][64], ampBn[4][64];  // SoA, invn folded into B

    int s0 = (T >> 8) - 1;
    // ---- phase A: global loads ----
    for (int i = tid; i < 640; i += 256)
        wf[i] = noise[(size_t)b * NSAMP + ((T - 127 + i) & NMASK)] * 2.0f - 1.0f;
    {
        const short8v* src = (const short8v*)(tapsA + ((size_t)b << 13));
        short8v* dst = (short8v*)R.tapsL;
        for (int i = tid; i < 1024; i += 256) dst[i] = src[i];
    }
    {
        int ad = tid >> 6, ah = tid & 63;
        int afr = min(max(s0 + ad, 0), 127);
        float aAv = ampT[(size_t)b * 16384 + afr * 128 + ah];
        float aBv = ampT[(size_t)b * 16384 + afr * 128 + 64 + ah];
        float invn = 1.0f / (__uint_as_float(maxb[b * 64 + ah]) + 1e-8f);
        ampA[ad][ah] = aAv;
        ampBn[ad][ah] = aBv * invn;
    }
    if (tid < 192) {
        int dd = tid >> 6, h2 = tid & 63;
        size_t vb = ((size_t)(b * 64 + h2)) * 128;
        int s = min(max(s0 + dd, 0), 127), s1 = min(s + 1, 127);
        float vs = vfreq[vb + s], vs1 = vfreq[vb + s1];
        float4 sgv;
        sgv.x = vs;
        sgv.y = (vs1 - vs) * (1.0f / 512.0f);
        sgv.z = PmodR[vb + s];
        sgv.w = 0.0f;
        seg[dd][h2] = sgv;
    }
    __syncthreads();
    // ---- phase B: wsh build, then templated core (fa/seg/amp hoists + main loop) ----
    for (int idx = tid; idx < 640; idx += 256) {
        int c = idx >> 3, s = idx & 7;
        short8v v;
#pragma unroll
        for (int e = 0; e < 8; ++e) {
            int t = 8 * c + e + s; t = t < 640 ? t : 639;
            v[e] = (short)f2bf(wf[t]);
        }
        *(short8v*)&wsh[s][8 * (c ^ s)] = v;
    }
    int shift = shiftb[b];
    switch (nmt) {
        case 1: final_core<1>(b, T, tid, s0, shift, R.tapsL, wsh, seg, ampA, ampBn, R.part, out); break;
        case 2: final_core<2>(b, T, tid, s0, shift, R.tapsL, wsh, seg, ampA, ampBn, R.part, out); break;
        case 3: final_core<3>(b, T, tid, s0, shift, R.tapsL, wsh, seg, ampA, ampBn, R.part, out); break;
        default: final_core<4>(b, T, tid, s0, shift, R.tapsL, wsh, seg, ampA, ampBn, R.part, out); break;
    }
}

extern "C" void kernel_launch(void* const* d_in, const int* in_sizes, int n_in,
                              void* d_out, int out_size, void* d_ws, size_t ws_size,
                              hipStream_t stream) {
    const float* x     = (const float*)d_in[0];
    const float* Wsw   = (const float*)d_in[1];
    const float* bsw   = (const float*)d_in[2];
    const float* Wf0   = (const float*)d_in[3];
    const float* bf0   = (const float*)d_in[4];
    const float* Wfv   = (const float*)d_in[5];
    const float* bfv   = (const float*)d_in[6];
    const float* Wamp  = (const float*)d_in[7];
    const float* bamp  = (const float*)d_in[8];
    const float* Wloc  = (const float*)d_in[9];
    const float* bloc  = (const float*)d_in[10];
    const float* usw   = (const float*)d_in[11];
    const float* uloc  = (const float*)d_in[12];
    const float* noise = (const float*)d_in[13];

    char* ws = (char*)d_ws;
    float*    PmodR  = (float*)(ws + OFF_PM);
    float*    vfreq  = (float*)(ws + OFF_V);
    unsigned short* tapsA = (unsigned short*)(ws + OFF_TA);
    float*    ampT   = (float*)(ws + OFF_A);
    unsigned* maxb   = (unsigned*)(ws + OFF_M);
    float*    swb    = (float*)(ws + OFF_SW);
    int*      shiftb = (int*)(ws + OFF_SH);
    int*      nmtb   = (int*)(ws + OFF_NM);
    float*    out    = (float*)d_out;

    setup_kernel<<<dim3(288), 256, 0, stream>>>(x, Wsw, bsw, Wf0, bf0, Wfv, bfv, Wamp, bamp,
                                                Wloc, bloc, usw, uloc, ampT,
                                                PmodR, vfreq, tapsA, swb, shiftb, maxb, nmtb);
    convmax_kernel<<<dim3(64, 32), 256, 0, stream>>>(noise, tapsA, swb, nmtb, maxb);
    final_kernel<<<dim3(64, 32), 256, 0, stream>>>(noise, tapsA, PmodR, vfreq, ampT, maxb,
                                                   swb, shiftb, nmtb, out);
}